// Round 6
// baseline (712.734 us; speedup 1.0000x reference)
//
#include <hip/hip_runtime.h>
#include <hip/hip_bf16.h>

#define Nn 50000
#define Ee 800000
#define INF_ 128
#define HIDF 96
#define HH 8
#define DD 12
#define GG 64
#define OUTF 10

#define SCAN_CHUNK 512
#define SCAN_BLOCKS ((Nn + SCAN_CHUNK - 1) / SCAN_CHUNK)   // 98
#define NSB ((Nn + 255) / 256)                             // 196
#define RB 128   // readout partial blocks

// byte-packed LDS histogram CSR build
#define HCHK 256                // edge chunks (= blocks)
#define HCHKE (Ee / HCHK)       // 3125 edges per chunk
#define NW 12512                // packed words: 4 keys/word, 50048 >= Nn
#define DBIN 64                 // degree bins for counting sort

// ---------------- hist pass A: single-pass dual byte-packed LDS histograms ----------------
__global__ __launch_bounds__(512) void hist_lds(const int* __restrict__ src,
                                                const int* __restrict__ dst,
                                                unsigned int* __restrict__ partS,
                                                unsigned int* __restrict__ partD,
                                                unsigned char* __restrict__ edge_slot) {
    __shared__ unsigned int hS[NW];
    __shared__ unsigned int hD[NW];
    int b = blockIdx.x, t = threadIdx.x;
    for (int i = t; i < NW; i += 512) { hS[i] = 0u; hD[i] = 0u; }
    __syncthreads();
    int base = b * HCHKE;
    for (int i = t; i < HCHKE; i += 512) {
        int d = dst[base + i];
        unsigned int old = atomicAdd(&hD[d >> 2], 1u << ((d & 3) * 8));
        edge_slot[base + i] = (unsigned char)((old >> ((d & 3) * 8)) & 0xFFu);
        int s = src[base + i];
        atomicAdd(&hS[s >> 2], 1u << ((s & 3) * 8));
    }
    __syncthreads();
    for (int i = t; i < NW; i += 512) {
        partD[(size_t)b * NW + i] = hD[i];
        partS[(size_t)b * NW + i] = hS[i];
    }
}

// ---------------- hist pass B ----------------
__global__ __launch_bounds__(256) void hist_scan(unsigned int* __restrict__ partD,
                                                 const unsigned int* __restrict__ partS,
                                                 int* __restrict__ cnt_in,
                                                 float* __restrict__ degI_is,
                                                 float* __restrict__ degO_is,
                                                 int* __restrict__ dcnt) {
    __shared__ int hbin[DBIN];
    int t = threadIdx.x;
    if (t < DBIN) hbin[t] = 0;
    __syncthreads();
    int w = blockIdx.x * 256 + t;
    if (w < NW) {
        unsigned int run = 0u, totS = 0u;
        for (int b = 0; b < HCHK; ++b) {
            size_t idx = (size_t)b * NW + w;
            unsigned int v = partD[idx];
            partD[idx] = run;               // exclusive prefix across chunks (packed bytes)
            run += v;
            totS += partS[idx];
        }
#pragma unroll
        for (int j = 0; j < 4; ++j) {
            int k = w * 4 + j;
            if (k < Nn) {
                int di = (int)((run >> (j * 8)) & 0xFFu);
                int dо = (int)((totS >> (j * 8)) & 0xFFu);
                cnt_in[k] = di;
                degI_is[k] = rsqrtf((float)max(di, 1));
                degO_is[k] = rsqrtf((float)max(dо, 1));
                atomicAdd(&hbin[DBIN - 1 - min(di, DBIN - 1)], 1);
            }
        }
    }
    __syncthreads();
    if (t < DBIN && hbin[t]) atomicAdd(&dcnt[t], hbin[t]);
}

// ---------------- hierarchical scan, stage 1 ----------------
__global__ __launch_bounds__(256) void scan1_kernel(const int* __restrict__ cnt,
                                                    int* __restrict__ row_start,
                                                    int* __restrict__ blk_sum, int N) {
    __shared__ int part[256];
    int t = threadIdx.x;
    int base = blockIdx.x * SCAN_CHUNK;
    int i0 = base + 2 * t, i1 = i0 + 1;
    int a = (i0 < N) ? cnt[i0] : 0;
    int b = (i1 < N) ? cnt[i1] : 0;
    int s = a + b;
    part[t] = s;
    __syncthreads();
    for (int off = 1; off < 256; off <<= 1) {
        int v = (t >= off) ? part[t - off] : 0;
        __syncthreads();
        part[t] += v;
        __syncthreads();
    }
    int excl = part[t] - s;
    if (i0 < N) row_start[i0] = excl;
    if (i1 < N) row_start[i1] = excl + a;
    if (t == 255) blk_sum[blockIdx.x] = part[255];
}

// ---------------- stage 2 (block 0) + degree-bin scan (block 1) ----------------
__global__ __launch_bounds__(128) void scan2_kernel(const int* __restrict__ blk_sum,
                                                    int* __restrict__ blk_off,
                                                    int* __restrict__ row_start,
                                                    const int* __restrict__ dcnt,
                                                    int* __restrict__ dcur, int N) {
    __shared__ int part[128];
    int t = threadIdx.x;
    if (blockIdx.x == 0) {
        int v0 = (t < SCAN_BLOCKS) ? blk_sum[t] : 0;
        part[t] = v0;
        __syncthreads();
        for (int off = 1; off < 128; off <<= 1) {
            int v = (t >= off) ? part[t - off] : 0;
            __syncthreads();
            part[t] += v;
            __syncthreads();
        }
        blk_off[t] = part[t] - v0;
        if (t == 127) row_start[N] = part[127];
    } else {
        int v0 = (t < DBIN) ? dcnt[t] : 0;
        part[t] = v0;
        __syncthreads();
        for (int off = 1; off < DBIN; off <<= 1) {
            int v = (t >= off) ? part[t - off] : 0;
            __syncthreads();
            part[t] += v;
            __syncthreads();
        }
        if (t < DBIN) dcur[t] = part[t] - v0;   // exclusive
    }
}

// ---------------- stage 3 + perm scatter ----------------
__global__ __launch_bounds__(256) void scan3_kernel(int* __restrict__ row_start,
                                                    const int* __restrict__ blk_off,
                                                    const int* __restrict__ cnt_in,
                                                    int* __restrict__ dcur,
                                                    int* __restrict__ perm, int N) {
    int t = threadIdx.x;
    if (blockIdx.x < SCAN_BLOCKS) {
        int base = blockIdx.x * SCAN_CHUNK;
        int off = blk_off[blockIdx.x];
        int i0 = base + 2 * t, i1 = i0 + 1;
        if (i0 < N) row_start[i0] += off;
        if (i1 < N) row_start[i1] += off;
    } else {
        __shared__ int lh[DBIN];
        __shared__ int lbase[DBIN];
        if (t < DBIN) lh[t] = 0;
        __syncthreads();
        int n = (blockIdx.x - SCAN_BLOCKS) * 256 + t;
        int bin = 0, lslot = 0;
        if (n < N) {
            bin = DBIN - 1 - min(cnt_in[n], DBIN - 1);
            lslot = atomicAdd(&lh[bin], 1);
        }
        __syncthreads();
        if (t < DBIN) lbase[t] = lh[t] ? atomicAdd(&dcur[t], lh[t]) : 0;
        __syncthreads();
        if (n < N) perm[lbase[bin] + lslot] = n;
    }
}

// ---------------- CSR fill: atomic-free ----------------
__global__ __launch_bounds__(512) void fill_kernel(const int* __restrict__ src,
                                                   const int* __restrict__ dst,
                                                   const int* __restrict__ row_start,
                                                   const unsigned int* __restrict__ partD,
                                                   const unsigned char* __restrict__ edge_slot,
                                                   int* __restrict__ csr_src) {
    int b = blockIdx.x, t = threadIdx.x;
    int base = b * HCHKE;
    size_t po = (size_t)b * NW;
    for (int i = t; i < HCHKE; i += 512) {
        int e = base + i;
        int d = dst[e];
        int cb = (int)((partD[po + (d >> 2)] >> ((d & 3) * 8)) & 0xFFu);
        csr_src[row_start[d] + cb + (int)edge_slot[e]] = src[e];
    }
}

// ---------------- SGPR-broadcast GEMM: W wave-uniform (scalar loads), ZERO LDS ----------------
// out[N x 96] = diag(rowScale) * A[N x K] @ W[K x 96] (+bias)
// R5 analysis: the LDS-W design costs 0.5 B/FMA of LDS -> 128 B/cy needed at
// VALU peak = exactly the LDS ceiling; plus 33-74KB LDS capped occupancy at
// 2-3 blocks/CU. New geometry: wave = 64 lanes = 64 rows; each of 8 waves owns
// a 12-col group (uniform via readfirstlane) -> W reads are wave-uniform
// s_loads into SGPRs, FMA uses the SGPR operand directly. No LDS, no barriers.
// A is read per-lane; the block's 8 waves reuse the same 64 rows via L1.
// k-order per (row,col) unchanged -> bit-exact vs previous rounds.
__global__ __launch_bounds__(512) void gemm96(const float* __restrict__ A, int K,
                                              const float* __restrict__ W,
                                              const float* __restrict__ bias,
                                              const float* __restrict__ rowScale,
                                              float* __restrict__ out, int N) {
    const int t = threadIdx.x;
    const int lane = t & 63;
    const int cb = __builtin_amdgcn_readfirstlane((t >> 6) * 12);   // col base, wave-uniform
    const int row = blockIdx.x * 64 + lane;
    const int grc = row < N ? row : N - 1;      // clamp: garbage rows never stored
    const float* __restrict__ Ap = A + (size_t)grc * K;
    const float* __restrict__ Wu = W + cb;      // uniform pointer -> scalar loads
    const float sc = rowScale ? rowScale[grc] : 1.f;

    float acc[12];
#pragma unroll
    for (int j = 0; j < 12; ++j) acc[j] = 0.f;

    float4 cur = *((const float4*)Ap);
    for (int k = 0; k < K; k += 4) {
        float4 nxt = (k + 4 < K) ? *((const float4*)(Ap + k + 4)) : cur;
#pragma unroll
        for (int kk = 0; kk < 4; ++kk) {
            float av = ((kk == 0) ? cur.x : (kk == 1) ? cur.y : (kk == 2) ? cur.z : cur.w) * sc;
#pragma unroll
            for (int j = 0; j < 12; ++j)
                acc[j] = fmaf(av, Wu[(k + kk) * 96 + j], acc[j]);
        }
        cur = nxt;
    }

    if (row < N) {
        float* op = out + (size_t)row * 96 + cb;
#pragma unroll
        for (int g = 0; g < 3; ++g) {
            float4 o;
            o.x = acc[4 * g + 0] + (bias ? bias[cb + 4 * g + 0] : 0.f);
            o.y = acc[4 * g + 1] + (bias ? bias[cb + 4 * g + 1] : 0.f);
            o.z = acc[4 * g + 2] + (bias ? bias[cb + 4 * g + 2] : 0.f);
            o.w = acc[4 * g + 3] + (bias ? bias[cb + 4 * g + 3] : 0.f);
            *((float4*)(op + 4 * g)) = o;
        }
    }
}

// ---------------- SGPR-broadcast dual GEMM (K=96), ZERO LDS ----------------
__global__ __launch_bounds__(512) void gemm96x2(const float* __restrict__ A,
                                                const float* __restrict__ W1_, const float* __restrict__ b1_,
                                                const float* __restrict__ W2_, const float* __restrict__ b2_,
                                                float* __restrict__ out1, float* __restrict__ out2, int N) {
    const int t = threadIdx.x;
    const int lane = t & 63;
    const int cb = __builtin_amdgcn_readfirstlane((t >> 6) * 12);   // col base, wave-uniform
    const int row = blockIdx.x * 64 + lane;
    const int grc = row < N ? row : N - 1;      // clamp: garbage rows never stored
    const float* __restrict__ Ap = A + (size_t)grc * 96;
    const float* __restrict__ W1u = W1_ + cb;   // uniform -> scalar loads
    const float* __restrict__ W2u = W2_ + cb;

    float acc1[12], acc2[12];
#pragma unroll
    for (int j = 0; j < 12; ++j) { acc1[j] = 0.f; acc2[j] = 0.f; }

    float4 cur = *((const float4*)Ap);
    for (int k = 0; k < 96; k += 4) {
        float4 nxt = (k + 4 < 96) ? *((const float4*)(Ap + k + 4)) : cur;
#pragma unroll
        for (int kk = 0; kk < 4; ++kk) {
            float av = (kk == 0) ? cur.x : (kk == 1) ? cur.y : (kk == 2) ? cur.z : cur.w;
#pragma unroll
            for (int j = 0; j < 12; ++j) {
                acc1[j] = fmaf(av, W1u[(k + kk) * 96 + j], acc1[j]);
                acc2[j] = fmaf(av, W2u[(k + kk) * 96 + j], acc2[j]);
            }
        }
        cur = nxt;
    }

    if (row < N) {
        float* op1 = out1 + (size_t)row * 96 + cb;
        float* op2 = out2 + (size_t)row * 96 + cb;
#pragma unroll
        for (int g = 0; g < 3; ++g) {
            float4 o1, o2;
            o1.x = acc1[4 * g + 0] + b1_[cb + 4 * g + 0];
            o1.y = acc1[4 * g + 1] + b1_[cb + 4 * g + 1];
            o1.z = acc1[4 * g + 2] + b1_[cb + 4 * g + 2];
            o1.w = acc1[4 * g + 3] + b1_[cb + 4 * g + 3];
            o2.x = acc2[4 * g + 0] + b2_[cb + 4 * g + 0];
            o2.y = acc2[4 * g + 1] + b2_[cb + 4 * g + 1];
            o2.z = acc2[4 * g + 2] + b2_[cb + 4 * g + 2];
            o2.w = acc2[4 * g + 3] + b2_[cb + 4 * g + 3];
            *((float4*)(op1 + 4 * g)) = o1;
            *((float4*)(op2 + 4 * g)) = o2;
        }
    }
}

// ---------------- GraphConv aggregate (degree-sorted via perm) ----------------
__global__ __launch_bounds__(192) void gc_agg(const float* __restrict__ hW,
                                              const int* __restrict__ row_start,
                                              const int* __restrict__ csr_src,
                                              const float* __restrict__ degI_is,
                                              const float* __restrict__ bias,
                                              const int* __restrict__ perm,
                                              float* __restrict__ hout, int N) {
    int tid = blockIdx.x * 192 + threadIdx.x;
    int p = tid / 24;
    int c = (tid % 24) * 4;
    if (p >= N) return;
    int n = perm[p];
    int beg = row_start[n], end = row_start[n + 1];
    float4 s = make_float4(0.f, 0.f, 0.f, 0.f);
    int e = beg;
    for (; e + 4 <= end; e += 4) {
        int i0 = csr_src[e], i1 = csr_src[e + 1], i2 = csr_src[e + 2], i3 = csr_src[e + 3];
        float4 v0 = *(const float4*)(hW + (size_t)i0 * 96 + c);
        float4 v1 = *(const float4*)(hW + (size_t)i1 * 96 + c);
        float4 v2 = *(const float4*)(hW + (size_t)i2 * 96 + c);
        float4 v3 = *(const float4*)(hW + (size_t)i3 * 96 + c);
        s.x += (v0.x + v1.x) + (v2.x + v3.x);
        s.y += (v0.y + v1.y) + (v2.y + v3.y);
        s.z += (v0.z + v1.z) + (v2.z + v3.z);
        s.w += (v0.w + v1.w) + (v2.w + v3.w);
    }
    for (; e < end; ++e) {
        int i0 = csr_src[e];
        float4 v0 = *(const float4*)(hW + (size_t)i0 * 96 + c);
        s.x += v0.x; s.y += v0.y; s.z += v0.z; s.w += v0.w;
    }
    float dn = degI_is[n];
    float4 b = *(const float4*)(bias + c);
    float4 o;
    o.x = fmaxf(fmaf(s.x, dn, b.x), 0.f);
    o.y = fmaxf(fmaf(s.y, dn, b.y), 0.f);
    o.z = fmaxf(fmaf(s.z, dn, b.z), 0.f);
    o.w = fmaxf(fmaf(s.w, dn, b.w), 0.f);
    *(float4*)(hout + (size_t)n * 96 + c) = o;
}

// ---------------- GATv2: 4-way edge-split per (node, head), shfl_xor butterfly merge ----------------
// R5: at the random-gather throughput ceiling (~2.6 TB/s read); occupancy 55%,
// dur invariant under 2x occupancy -> leave as-is.
__global__ __launch_bounds__(256) void gat_agg(const float* __restrict__ fs,
                                               const float* __restrict__ fd,
                                               const float* __restrict__ attn,
                                               const int* __restrict__ row_start,
                                               const int* __restrict__ csr_src,
                                               const int* __restrict__ perm,
                                               float* __restrict__ hout, int N) {
    int tid = blockIdx.x * 256 + threadIdx.x;
    int p = tid >> 5;           // node (perm index)
    int hd = (tid >> 2) & 7;    // head
    int q = tid & 3;            // edge quarter
    if (p >= N) return;
    int n = perm[p];
    float att[12], fdv[12];
    {
        const float4* ap = (const float4*)(attn + hd * 12);
        float4 a0 = ap[0], a1 = ap[1], a2 = ap[2];
        att[0]=a0.x; att[1]=a0.y; att[2]=a0.z; att[3]=a0.w;
        att[4]=a1.x; att[5]=a1.y; att[6]=a1.z; att[7]=a1.w;
        att[8]=a2.x; att[9]=a2.y; att[10]=a2.z; att[11]=a2.w;
        const float4* dp = (const float4*)(fd + (size_t)n * 96 + hd * 12);
        float4 d0 = dp[0], d1 = dp[1], d2 = dp[2];
        fdv[0]=d0.x; fdv[1]=d0.y; fdv[2]=d0.z; fdv[3]=d0.w;
        fdv[4]=d1.x; fdv[5]=d1.y; fdv[6]=d1.z; fdv[7]=d1.w;
        fdv[8]=d2.x; fdv[9]=d2.y; fdv[10]=d2.z; fdv[11]=d2.w;
    }
    int beg = row_start[n], end = row_start[n + 1];
    float m = -3.0e38f, den = 0.f;
    float A[12];
#pragma unroll
    for (int d = 0; d < 12; ++d) A[d] = 0.f;

    for (int e = beg + q; e < end; e += 4) {
        int i0 = csr_src[e];
        const float4* p0 = (const float4*)(fs + (size_t)i0 * 96 + hd * 12);
        float4 s0 = p0[0], s1 = p0[1], s2 = p0[2];
        float fsv[12];
        fsv[0]=s0.x; fsv[1]=s0.y; fsv[2]=s0.z; fsv[3]=s0.w;
        fsv[4]=s1.x; fsv[5]=s1.y; fsv[6]=s1.z; fsv[7]=s1.w;
        fsv[8]=s2.x; fsv[9]=s2.y; fsv[10]=s2.z; fsv[11]=s2.w;
        float logit = 0.f;
#pragma unroll
        for (int d = 0; d < 12; ++d) {
            float u = fsv[d] + fdv[d];
            u = u > 0.f ? u : 0.2f * u;
            logit = fmaf(u, att[d], logit);
        }
        float nm = fmaxf(m, logit);
        float cc = __expf(m - nm);
        float w  = __expf(logit - nm);
        den = fmaf(den, cc, w);
#pragma unroll
        for (int d = 0; d < 12; ++d) A[d] = fmaf(A[d], cc, w * fsv[d]);
        m = nm;
    }

    // butterfly merge across the 4 q-lanes (all lanes end with the full state)
#pragma unroll
    for (int off = 1; off <= 2; off <<= 1) {
        float m2   = __shfl_xor(m, off, 64);
        float den2 = __shfl_xor(den, off, 64);
        float nm = fmaxf(m, m2);
        float c1 = __expf(m - nm);
        float c2 = __expf(m2 - nm);
        den = den * c1 + den2 * c2;
#pragma unroll
        for (int d = 0; d < 12; ++d) {
            float a2 = __shfl_xor(A[d], off, 64);
            A[d] = A[d] * c1 + a2 * c2;
        }
        m = nm;
    }

    float inv = den > 0.f ? 1.f / den : 0.f;
    float* op = hout + (size_t)n * 96 + hd * 12;
    // each q-lane writes 3 of the 12 outputs
#pragma unroll
    for (int j = 0; j < 3; ++j) {
        int d = q * 3 + j;
        float v = (d == 0) ? A[0] : (d == 1) ? A[1] : (d == 2) ? A[2] : (d == 3) ? A[3]
                : (d == 4) ? A[4] : (d == 5) ? A[5] : (d == 6) ? A[6] : (d == 7) ? A[7]
                : (d == 8) ? A[8] : (d == 9) ? A[9] : (d == 10) ? A[10] : A[11];
        op[d] = fmaxf(v * inv, 0.f);
    }
}

// ---------------- per-graph max readout: stage 1 ----------------
__global__ __launch_bounds__(384) void readout_partial(const float* __restrict__ h,
                                                       const int* __restrict__ graph_id,
                                                       float* __restrict__ partial, int N) {
    __shared__ int lhg[GG * 96];
    int t = threadIdx.x;
    for (int i = t; i < GG * 96; i += 384) lhg[i] = 0;
    __syncthreads();
    int f = t % 96, nl = t / 96;
    for (int n0 = blockIdx.x * 4; n0 < N; n0 += RB * 4) {
        int n = n0 + nl;
        if (n < N) {
            int g = graph_id[n];
            float v = h[(size_t)n * 96 + f];
            atomicMax(&lhg[g * 96 + f], __float_as_int(v));
        }
    }
    __syncthreads();
    for (int i = t; i < GG * 96; i += 384)
        partial[(size_t)blockIdx.x * (GG * 96) + i] = __int_as_float(lhg[i]);
}

// ---------------- readout stage 2: reduce partials ----------------
__global__ void readout_reduce(const float* __restrict__ partial, float* __restrict__ hg) {
    int i = blockIdx.x * 256 + threadIdx.x;
    if (i < GG * 96) {
        float m = 0.f;
        for (int b = 0; b < RB; ++b) m = fmaxf(m, partial[(size_t)b * (GG * 96) + i]);
        hg[i] = m;
    }
}

// ---------------- classifier MLP: one block per graph ----------------
__global__ __launch_bounds__(96) void mlp_kernel(const float* __restrict__ hg,
                                                 const float* __restrict__ Wc1, const float* __restrict__ bc1,
                                                 const float* __restrict__ Wc2, const float* __restrict__ bc2,
                                                 const float* __restrict__ Wc3, const float* __restrict__ bc3,
                                                 float* __restrict__ out) {
    int g = blockIdx.x;
    int t = threadIdx.x;
    __shared__ float z0[96], z1[96], z2[48];
    z0[t] = hg[(size_t)g * 96 + t];
    __syncthreads();
    float s = bc1[t];
    for (int k = 0; k < 96; ++k) s = fmaf(z0[k], Wc1[k * 96 + t], s);
    z1[t] = fmaxf(s, 0.f);
    __syncthreads();
    if (t < 48) {
        float s2 = bc2[t];
        for (int k = 0; k < 96; ++k) s2 = fmaf(z1[k], Wc2[k * 48 + t], s2);
        z2[t] = fmaxf(s2, 0.f);
    }
    __syncthreads();
    if (t < 10) {
        float s3 = bc3[t];
        for (int k = 0; k < 48; ++k) s3 = fmaf(z2[k], Wc3[k * 10 + t], s3);
        out[(size_t)g * 10 + t] = s3;
    }
}

extern "C" void kernel_launch(void* const* d_in, const int* in_sizes, int n_in,
                              void* d_out, int out_size, void* d_ws, size_t ws_size,
                              hipStream_t stream) {
    const float* x        = (const float*)d_in[0];
    const int*   src      = (const int*)d_in[1];
    const int*   dst      = (const int*)d_in[2];
    const int*   graph_id = (const int*)d_in[3];
    const float* W1  = (const float*)d_in[4];
    const float* b1  = (const float*)d_in[5];
    const float* W2  = (const float*)d_in[6];
    const float* b2  = (const float*)d_in[7];
    const float* Ws  = (const float*)d_in[8];
    const float* bs  = (const float*)d_in[9];
    const float* Wd  = (const float*)d_in[10];
    const float* bd  = (const float*)d_in[11];
    const float* attn = (const float*)d_in[12];
    const float* Wc1 = (const float*)d_in[13];
    const float* bc1 = (const float*)d_in[14];
    const float* Wc2 = (const float*)d_in[15];
    const float* bc2 = (const float*)d_in[16];
    const float* Wc3 = (const float*)d_in[17];
    const float* bc3 = (const float*)d_in[18];
    float* out = (float*)d_out;

    char* ws = (char*)d_ws;
    size_t off = 0;
    auto alloc = [&](size_t bytes) {
        char* p = ws + off;
        off = (off + bytes + 255) & ~(size_t)255;
        return p;
    };
    int*   cnt_in    = (int*)alloc(Nn * 4);
    int*   row_start = (int*)alloc((Nn + 1) * 4);
    unsigned char* edge_slot = (unsigned char*)alloc(Ee);
    int*   csr_src   = (int*)alloc(Ee * 4);
    int*   perm      = (int*)alloc(Nn * 4);
    float* degI_is   = (float*)alloc(Nn * 4);
    float* degO_is   = (float*)alloc(Nn * 4);
    float* bufH      = (float*)alloc((size_t)Nn * 96 * 4);
    float* bufT      = (float*)alloc((size_t)Nn * 96 * 4);
    float* bufFd     = (float*)alloc((size_t)Nn * 96 * 4);
    float* hg        = (float*)alloc(GG * 96 * 4);
    float* partial   = (float*)alloc((size_t)RB * GG * 96 * 4);
    int*   blk_sum   = (int*)alloc(128 * 4);
    int*   blk_off   = (int*)alloc(128 * 4);
    int*   dcnt      = (int*)alloc(DBIN * 4);
    int*   dcur      = (int*)alloc(DBIN * 4);

    // packed histogram partials alias the (not-yet-used) feature buffers:
    // HCHK*NW*4 = 12.8 MB each; bufT/bufFd are 19.2 MB each.
    unsigned int* partS = (unsigned int*)bufT;
    unsigned int* partD = (unsigned int*)bufFd;

    hipMemsetAsync(dcnt, 0, DBIN * 4, stream);

    // ---- CSR build + degrees + degree-sort (no global fp atomics, 6 kernels) ----
    hist_lds<<<HCHK, 512, 0, stream>>>(src, dst, partS, partD, edge_slot);
    hist_scan<<<(NW + 255) / 256, 256, 0, stream>>>(partD, partS, cnt_in, degI_is, degO_is, dcnt);
    scan1_kernel<<<SCAN_BLOCKS, 256, 0, stream>>>(cnt_in, row_start, blk_sum, Nn);
    scan2_kernel<<<2, 128, 0, stream>>>(blk_sum, blk_off, row_start, dcnt, dcur, Nn);
    scan3_kernel<<<SCAN_BLOCKS + NSB, 256, 0, stream>>>(row_start, blk_off, cnt_in, dcur, perm, Nn);
    fill_kernel<<<HCHK, 512, 0, stream>>>(src, dst, row_start, partD, edge_slot, csr_src);

    int gemm_blocks = (Nn + 63) / 64;                  // 64 rows per 512-thread block
    int agg_blocks  = (Nn * 24 + 191) / 192;
    int gat_blocks  = (Nn * 32 + 255) / 256;           // 4-way edge-split: 32 threads/node

    // GraphConv 1: x[N,128] -> bufH
    gemm96<<<gemm_blocks, 512, 0, stream>>>(x, 128, W1, nullptr, degO_is, bufT, Nn);
    gc_agg<<<agg_blocks, 192, 0, stream>>>(bufT, row_start, csr_src, degI_is, b1, perm, bufH, Nn);
    // GraphConv 2
    gemm96<<<gemm_blocks, 512, 0, stream>>>(bufH, 96, W2, nullptr, degO_is, bufT, Nn);
    gc_agg<<<agg_blocks, 192, 0, stream>>>(bufT, row_start, csr_src, degI_is, b2, perm, bufH, Nn);

    // 3x GATv2: fused dual GEMM (fs,fd) then fused attention+aggregate
    for (int l = 0; l < 3; ++l) {
        const float* Wsl = Ws + (size_t)l * 96 * 96;
        const float* bsl = bs + (size_t)l * 96;
        const float* Wdl = Wd + (size_t)l * 96 * 96;
        const float* bdl = bd + (size_t)l * 96;
        const float* atl = attn + (size_t)l * 96;
        gemm96x2<<<gemm_blocks, 512, 0, stream>>>(bufH, Wsl, bsl, Wdl, bdl, bufT, bufFd, Nn);
        gat_agg<<<gat_blocks, 256, 0, stream>>>(bufT, bufFd, atl, row_start, csr_src, perm, bufH, Nn);
    }

    readout_partial<<<RB, 384, 0, stream>>>(bufH, graph_id, partial, Nn);
    readout_reduce<<<(GG * 96 + 255) / 256, 256, 0, stream>>>(partial, hg);
    mlp_kernel<<<GG, 96, 0, stream>>>(hg, Wc1, bc1, Wc2, bc2, Wc3, bc3, out);
}

// Round 7
// 621.963 us; speedup vs baseline: 1.1459x; 1.1459x over previous
//
#include <hip/hip_runtime.h>
#include <hip/hip_bf16.h>

#define Nn 50000
#define Ee 800000
#define INF_ 128
#define HIDF 96
#define HH 8
#define DD 12
#define GG 64
#define OUTF 10

#define SCAN_CHUNK 512
#define SCAN_BLOCKS ((Nn + SCAN_CHUNK - 1) / SCAN_CHUNK)   // 98
#define NSB ((Nn + 255) / 256)                             // 196
#define RB 128   // readout partial blocks

// byte-packed LDS histogram CSR build
#define HCHK 256                // edge chunks (= blocks)
#define HCHKE (Ee / HCHK)       // 3125 edges per chunk
#define NW 12512                // packed words: 4 keys/word, 50048 >= Nn
#define DBIN 64                 // degree bins for counting sort

// ---------------- hist pass A: single-pass dual byte-packed LDS histograms ----------------
__global__ __launch_bounds__(512) void hist_lds(const int* __restrict__ src,
                                                const int* __restrict__ dst,
                                                unsigned int* __restrict__ partS,
                                                unsigned int* __restrict__ partD,
                                                unsigned char* __restrict__ edge_slot) {
    __shared__ unsigned int hS[NW];
    __shared__ unsigned int hD[NW];
    int b = blockIdx.x, t = threadIdx.x;
    for (int i = t; i < NW; i += 512) { hS[i] = 0u; hD[i] = 0u; }
    __syncthreads();
    int base = b * HCHKE;
    for (int i = t; i < HCHKE; i += 512) {
        int d = dst[base + i];
        unsigned int old = atomicAdd(&hD[d >> 2], 1u << ((d & 3) * 8));
        edge_slot[base + i] = (unsigned char)((old >> ((d & 3) * 8)) & 0xFFu);
        int s = src[base + i];
        atomicAdd(&hS[s >> 2], 1u << ((s & 3) * 8));
    }
    __syncthreads();
    for (int i = t; i < NW; i += 512) {
        partD[(size_t)b * NW + i] = hD[i];
        partS[(size_t)b * NW + i] = hS[i];
    }
}

// ---------------- hist pass B ----------------
__global__ __launch_bounds__(256) void hist_scan(unsigned int* __restrict__ partD,
                                                 const unsigned int* __restrict__ partS,
                                                 int* __restrict__ cnt_in,
                                                 float* __restrict__ degI_is,
                                                 float* __restrict__ degO_is,
                                                 int* __restrict__ dcnt) {
    __shared__ int hbin[DBIN];
    int t = threadIdx.x;
    if (t < DBIN) hbin[t] = 0;
    __syncthreads();
    int w = blockIdx.x * 256 + t;
    if (w < NW) {
        unsigned int run = 0u, totS = 0u;
        for (int b = 0; b < HCHK; ++b) {
            size_t idx = (size_t)b * NW + w;
            unsigned int v = partD[idx];
            partD[idx] = run;               // exclusive prefix across chunks (packed bytes)
            run += v;
            totS += partS[idx];
        }
#pragma unroll
        for (int j = 0; j < 4; ++j) {
            int k = w * 4 + j;
            if (k < Nn) {
                int di = (int)((run >> (j * 8)) & 0xFFu);
                int dо = (int)((totS >> (j * 8)) & 0xFFu);
                cnt_in[k] = di;
                degI_is[k] = rsqrtf((float)max(di, 1));
                degO_is[k] = rsqrtf((float)max(dо, 1));
                atomicAdd(&hbin[DBIN - 1 - min(di, DBIN - 1)], 1);
            }
        }
    }
    __syncthreads();
    if (t < DBIN && hbin[t]) atomicAdd(&dcnt[t], hbin[t]);
}

// ---------------- hierarchical scan, stage 1 ----------------
__global__ __launch_bounds__(256) void scan1_kernel(const int* __restrict__ cnt,
                                                    int* __restrict__ row_start,
                                                    int* __restrict__ blk_sum, int N) {
    __shared__ int part[256];
    int t = threadIdx.x;
    int base = blockIdx.x * SCAN_CHUNK;
    int i0 = base + 2 * t, i1 = i0 + 1;
    int a = (i0 < N) ? cnt[i0] : 0;
    int b = (i1 < N) ? cnt[i1] : 0;
    int s = a + b;
    part[t] = s;
    __syncthreads();
    for (int off = 1; off < 256; off <<= 1) {
        int v = (t >= off) ? part[t - off] : 0;
        __syncthreads();
        part[t] += v;
        __syncthreads();
    }
    int excl = part[t] - s;
    if (i0 < N) row_start[i0] = excl;
    if (i1 < N) row_start[i1] = excl + a;
    if (t == 255) blk_sum[blockIdx.x] = part[255];
}

// ---------------- stage 2 (block 0) + degree-bin scan (block 1) ----------------
__global__ __launch_bounds__(128) void scan2_kernel(const int* __restrict__ blk_sum,
                                                    int* __restrict__ blk_off,
                                                    int* __restrict__ row_start,
                                                    const int* __restrict__ dcnt,
                                                    int* __restrict__ dcur, int N) {
    __shared__ int part[128];
    int t = threadIdx.x;
    if (blockIdx.x == 0) {
        int v0 = (t < SCAN_BLOCKS) ? blk_sum[t] : 0;
        part[t] = v0;
        __syncthreads();
        for (int off = 1; off < 128; off <<= 1) {
            int v = (t >= off) ? part[t - off] : 0;
            __syncthreads();
            part[t] += v;
            __syncthreads();
        }
        blk_off[t] = part[t] - v0;
        if (t == 127) row_start[N] = part[127];
    } else {
        int v0 = (t < DBIN) ? dcnt[t] : 0;
        part[t] = v0;
        __syncthreads();
        for (int off = 1; off < DBIN; off <<= 1) {
            int v = (t >= off) ? part[t - off] : 0;
            __syncthreads();
            part[t] += v;
            __syncthreads();
        }
        if (t < DBIN) dcur[t] = part[t] - v0;   // exclusive
    }
}

// ---------------- stage 3 + perm scatter ----------------
__global__ __launch_bounds__(256) void scan3_kernel(int* __restrict__ row_start,
                                                    const int* __restrict__ blk_off,
                                                    const int* __restrict__ cnt_in,
                                                    int* __restrict__ dcur,
                                                    int* __restrict__ perm, int N) {
    int t = threadIdx.x;
    if (blockIdx.x < SCAN_BLOCKS) {
        int base = blockIdx.x * SCAN_CHUNK;
        int off = blk_off[blockIdx.x];
        int i0 = base + 2 * t, i1 = i0 + 1;
        if (i0 < N) row_start[i0] += off;
        if (i1 < N) row_start[i1] += off;
    } else {
        __shared__ int lh[DBIN];
        __shared__ int lbase[DBIN];
        if (t < DBIN) lh[t] = 0;
        __syncthreads();
        int n = (blockIdx.x - SCAN_BLOCKS) * 256 + t;
        int bin = 0, lslot = 0;
        if (n < N) {
            bin = DBIN - 1 - min(cnt_in[n], DBIN - 1);
            lslot = atomicAdd(&lh[bin], 1);
        }
        __syncthreads();
        if (t < DBIN) lbase[t] = lh[t] ? atomicAdd(&dcur[t], lh[t]) : 0;
        __syncthreads();
        if (n < N) perm[lbase[bin] + lslot] = n;
    }
}

// ---------------- CSR fill: atomic-free ----------------
__global__ __launch_bounds__(512) void fill_kernel(const int* __restrict__ src,
                                                   const int* __restrict__ dst,
                                                   const int* __restrict__ row_start,
                                                   const unsigned int* __restrict__ partD,
                                                   const unsigned char* __restrict__ edge_slot,
                                                   int* __restrict__ csr_src) {
    int b = blockIdx.x, t = threadIdx.x;
    int base = b * HCHKE;
    size_t po = (size_t)b * NW;
    for (int i = t; i < HCHKE; i += 512) {
        int e = base + i;
        int d = dst[e];
        int cb = (int)((partD[po + (d >> 2)] >> ((d & 3) * 8)) & 0xFFu);
        csr_src[row_start[d] + cb + (int)edge_slot[e]] = src[e];
    }
}

// ---------------- chunked-W LDS GEMM: 18.4KB LDS -> high occupancy ----------------
// out[N x 96] = diag(rowScale) * A[N x K] @ W[K x 96] (+bias)
// R6: scalar-path W streaming failed (SMEM bottleneck, VALUBusy 17%). R5's
// full-W-LDS design was TLP-starved: 49-74KB LDS -> 1.5-2.25 waves/SIMD.
// Fix: stage W in 48-k chunks (18.4KB) with 2 barriers per chunk (amortized
// over ~2400cy of FMA each, unlike R0's per-32k drain); no reg-prefetch so
// VGPR stays ~100 -> ~4.5 waves/SIMD. Inner loop identical to R4 (bit-exact:
// k strictly ascending per (row,col), av = a*sc then fma).
#define KC 48
__global__ __launch_bounds__(192) void gemm96(const float* __restrict__ A, int K,
                                              const float* __restrict__ W,
                                              const float* __restrict__ bias,
                                              const float* __restrict__ rowScale,
                                              float* __restrict__ out, int N) {
    __shared__ float W_lds[KC * 96];   // 18432 B
    const int t = threadIdx.x;
    const int row0 = blockIdx.x * 64;
    const int tcol = t % 24;
    const int trow = t / 24;

    const float* Ap[8];
    float sc[8];
#pragma unroll
    for (int i = 0; i < 8; ++i) {
        int gr = row0 + trow + 8 * i;
        gr = gr < N ? gr : N - 1;           // clamp: garbage rows never stored
        Ap[i] = A + (size_t)gr * K;
        sc[i] = rowScale ? rowScale[gr] : 1.f;
    }
    float acc[8][4];
#pragma unroll
    for (int i = 0; i < 8; ++i)
#pragma unroll
        for (int j = 0; j < 4; ++j) acc[i][j] = 0.f;

    for (int kc = 0; kc < K; kc += KC) {
        int klen = (K - kc) < KC ? (K - kc) : KC;
        __syncthreads();                    // protect previous chunk's readers
        for (int i = t; i < klen * 24; i += 192)
            ((float4*)W_lds)[i] = ((const float4*)W)[kc * 24 + i];
        __syncthreads();
        for (int k = 0; k < klen; k += 4) {
            float4 a[8];
#pragma unroll
            for (int i = 0; i < 8; ++i)
                a[i] = *((const float4*)(Ap[i] + kc + k));
#pragma unroll
            for (int kk = 0; kk < 4; ++kk) {
                float4 wv = *((const float4*)(W_lds + (k + kk) * 96 + tcol * 4));
#pragma unroll
                for (int i = 0; i < 8; ++i) {
                    float av = ((kk == 0) ? a[i].x : (kk == 1) ? a[i].y
                               : (kk == 2) ? a[i].z : a[i].w) * sc[i];
                    acc[i][0] = fmaf(av, wv.x, acc[i][0]);
                    acc[i][1] = fmaf(av, wv.y, acc[i][1]);
                    acc[i][2] = fmaf(av, wv.z, acc[i][2]);
                    acc[i][3] = fmaf(av, wv.w, acc[i][3]);
                }
            }
        }
    }
    float4 b4 = bias ? *((const float4*)(bias + tcol * 4)) : make_float4(0.f, 0.f, 0.f, 0.f);
#pragma unroll
    for (int i = 0; i < 8; ++i) {
        int gr = row0 + trow + 8 * i;
        if (gr < N) {
            float4 o = make_float4(acc[i][0] + b4.x, acc[i][1] + b4.y,
                                   acc[i][2] + b4.z, acc[i][3] + b4.w);
            *((float4*)(out + (size_t)gr * 96 + tcol * 4)) = o;
        }
    }
}

// ---------------- chunked-W dual GEMM (K=96): 2 x 24-k chunks = 18.4KB LDS ----------------
#define KC2 24
__global__ __launch_bounds__(192) void gemm96x2(const float* __restrict__ A,
                                                const float* __restrict__ W1_, const float* __restrict__ b1_,
                                                const float* __restrict__ W2_, const float* __restrict__ b2_,
                                                float* __restrict__ out1, float* __restrict__ out2, int N) {
    __shared__ float W_lds[2 * KC2 * 96];   // 18432 B
    const int t = threadIdx.x;
    const int row0 = blockIdx.x * 64;
    const int tcol = t % 24;
    const int trow = t / 24;

    const float* Ap[8];
#pragma unroll
    for (int i = 0; i < 8; ++i) {
        int gr = row0 + trow + 8 * i;
        gr = gr < N ? gr : N - 1;           // clamp: garbage rows never stored
        Ap[i] = A + (size_t)gr * 96;
    }
    float acc1[8][4], acc2[8][4];
#pragma unroll
    for (int i = 0; i < 8; ++i)
#pragma unroll
        for (int j = 0; j < 4; ++j) { acc1[i][j] = 0.f; acc2[i][j] = 0.f; }

    for (int kc = 0; kc < 96; kc += KC2) {
        __syncthreads();                    // protect previous chunk's readers
        for (int i = t; i < KC2 * 24; i += 192) {
            ((float4*)W_lds)[i] = ((const float4*)W1_)[kc * 24 + i];
            ((float4*)(W_lds + KC2 * 96))[i] = ((const float4*)W2_)[kc * 24 + i];
        }
        __syncthreads();
        for (int k = 0; k < KC2; k += 4) {
            float4 a[8];
#pragma unroll
            for (int i = 0; i < 8; ++i)
                a[i] = *((const float4*)(Ap[i] + kc + k));
#pragma unroll
            for (int kk = 0; kk < 4; ++kk) {
                float4 wv1 = *((const float4*)(W_lds + (k + kk) * 96 + tcol * 4));
                float4 wv2 = *((const float4*)(W_lds + KC2 * 96 + (k + kk) * 96 + tcol * 4));
#pragma unroll
                for (int i = 0; i < 8; ++i) {
                    float av = (kk == 0) ? a[i].x : (kk == 1) ? a[i].y : (kk == 2) ? a[i].z : a[i].w;
                    acc1[i][0] = fmaf(av, wv1.x, acc1[i][0]);
                    acc1[i][1] = fmaf(av, wv1.y, acc1[i][1]);
                    acc1[i][2] = fmaf(av, wv1.z, acc1[i][2]);
                    acc1[i][3] = fmaf(av, wv1.w, acc1[i][3]);
                    acc2[i][0] = fmaf(av, wv2.x, acc2[i][0]);
                    acc2[i][1] = fmaf(av, wv2.y, acc2[i][1]);
                    acc2[i][2] = fmaf(av, wv2.z, acc2[i][2]);
                    acc2[i][3] = fmaf(av, wv2.w, acc2[i][3]);
                }
            }
        }
    }
    float4 bb1 = *((const float4*)(b1_ + tcol * 4));
    float4 bb2 = *((const float4*)(b2_ + tcol * 4));
#pragma unroll
    for (int i = 0; i < 8; ++i) {
        int gr = row0 + trow + 8 * i;
        if (gr < N) {
            float4 o1 = make_float4(acc1[i][0] + bb1.x, acc1[i][1] + bb1.y,
                                    acc1[i][2] + bb1.z, acc1[i][3] + bb1.w);
            float4 o2 = make_float4(acc2[i][0] + bb2.x, acc2[i][1] + bb2.y,
                                    acc2[i][2] + bb2.z, acc2[i][3] + bb2.w);
            *((float4*)(out1 + (size_t)gr * 96 + tcol * 4)) = o1;
            *((float4*)(out2 + (size_t)gr * 96 + tcol * 4)) = o2;
        }
    }
}

// ---------------- GraphConv aggregate (degree-sorted via perm) ----------------
__global__ __launch_bounds__(192) void gc_agg(const float* __restrict__ hW,
                                              const int* __restrict__ row_start,
                                              const int* __restrict__ csr_src,
                                              const float* __restrict__ degI_is,
                                              const float* __restrict__ bias,
                                              const int* __restrict__ perm,
                                              float* __restrict__ hout, int N) {
    int tid = blockIdx.x * 192 + threadIdx.x;
    int p = tid / 24;
    int c = (tid % 24) * 4;
    if (p >= N) return;
    int n = perm[p];
    int beg = row_start[n], end = row_start[n + 1];
    float4 s = make_float4(0.f, 0.f, 0.f, 0.f);
    int e = beg;
    for (; e + 4 <= end; e += 4) {
        int i0 = csr_src[e], i1 = csr_src[e + 1], i2 = csr_src[e + 2], i3 = csr_src[e + 3];
        float4 v0 = *(const float4*)(hW + (size_t)i0 * 96 + c);
        float4 v1 = *(const float4*)(hW + (size_t)i1 * 96 + c);
        float4 v2 = *(const float4*)(hW + (size_t)i2 * 96 + c);
        float4 v3 = *(const float4*)(hW + (size_t)i3 * 96 + c);
        s.x += (v0.x + v1.x) + (v2.x + v3.x);
        s.y += (v0.y + v1.y) + (v2.y + v3.y);
        s.z += (v0.z + v1.z) + (v2.z + v3.z);
        s.w += (v0.w + v1.w) + (v2.w + v3.w);
    }
    for (; e < end; ++e) {
        int i0 = csr_src[e];
        float4 v0 = *(const float4*)(hW + (size_t)i0 * 96 + c);
        s.x += v0.x; s.y += v0.y; s.z += v0.z; s.w += v0.w;
    }
    float dn = degI_is[n];
    float4 b = *(const float4*)(bias + c);
    float4 o;
    o.x = fmaxf(fmaf(s.x, dn, b.x), 0.f);
    o.y = fmaxf(fmaf(s.y, dn, b.y), 0.f);
    o.z = fmaxf(fmaf(s.z, dn, b.z), 0.f);
    o.w = fmaxf(fmaf(s.w, dn, b.w), 0.f);
    *(float4*)(hout + (size_t)n * 96 + c) = o;
}

// ---------------- GATv2: 4-way edge-split per (node, head), shfl_xor butterfly merge ----------------
// R5: at the random-gather throughput ceiling (~2.6 TB/s read); occupancy 55%,
// dur invariant under 2x occupancy -> leave as-is.
__global__ __launch_bounds__(256) void gat_agg(const float* __restrict__ fs,
                                               const float* __restrict__ fd,
                                               const float* __restrict__ attn,
                                               const int* __restrict__ row_start,
                                               const int* __restrict__ csr_src,
                                               const int* __restrict__ perm,
                                               float* __restrict__ hout, int N) {
    int tid = blockIdx.x * 256 + threadIdx.x;
    int p = tid >> 5;           // node (perm index)
    int hd = (tid >> 2) & 7;    // head
    int q = tid & 3;            // edge quarter
    if (p >= N) return;
    int n = perm[p];
    float att[12], fdv[12];
    {
        const float4* ap = (const float4*)(attn + hd * 12);
        float4 a0 = ap[0], a1 = ap[1], a2 = ap[2];
        att[0]=a0.x; att[1]=a0.y; att[2]=a0.z; att[3]=a0.w;
        att[4]=a1.x; att[5]=a1.y; att[6]=a1.z; att[7]=a1.w;
        att[8]=a2.x; att[9]=a2.y; att[10]=a2.z; att[11]=a2.w;
        const float4* dp = (const float4*)(fd + (size_t)n * 96 + hd * 12);
        float4 d0 = dp[0], d1 = dp[1], d2 = dp[2];
        fdv[0]=d0.x; fdv[1]=d0.y; fdv[2]=d0.z; fdv[3]=d0.w;
        fdv[4]=d1.x; fdv[5]=d1.y; fdv[6]=d1.z; fdv[7]=d1.w;
        fdv[8]=d2.x; fdv[9]=d2.y; fdv[10]=d2.z; fdv[11]=d2.w;
    }
    int beg = row_start[n], end = row_start[n + 1];
    float m = -3.0e38f, den = 0.f;
    float A[12];
#pragma unroll
    for (int d = 0; d < 12; ++d) A[d] = 0.f;

    for (int e = beg + q; e < end; e += 4) {
        int i0 = csr_src[e];
        const float4* p0 = (const float4*)(fs + (size_t)i0 * 96 + hd * 12);
        float4 s0 = p0[0], s1 = p0[1], s2 = p0[2];
        float fsv[12];
        fsv[0]=s0.x; fsv[1]=s0.y; fsv[2]=s0.z; fsv[3]=s0.w;
        fsv[4]=s1.x; fsv[5]=s1.y; fsv[6]=s1.z; fsv[7]=s1.w;
        fsv[8]=s2.x; fsv[9]=s2.y; fsv[10]=s2.z; fsv[11]=s2.w;
        float logit = 0.f;
#pragma unroll
        for (int d = 0; d < 12; ++d) {
            float u = fsv[d] + fdv[d];
            u = u > 0.f ? u : 0.2f * u;
            logit = fmaf(u, att[d], logit);
        }
        float nm = fmaxf(m, logit);
        float cc = __expf(m - nm);
        float w  = __expf(logit - nm);
        den = fmaf(den, cc, w);
#pragma unroll
        for (int d = 0; d < 12; ++d) A[d] = fmaf(A[d], cc, w * fsv[d]);
        m = nm;
    }

    // butterfly merge across the 4 q-lanes (all lanes end with the full state)
#pragma unroll
    for (int off = 1; off <= 2; off <<= 1) {
        float m2   = __shfl_xor(m, off, 64);
        float den2 = __shfl_xor(den, off, 64);
        float nm = fmaxf(m, m2);
        float c1 = __expf(m - nm);
        float c2 = __expf(m2 - nm);
        den = den * c1 + den2 * c2;
#pragma unroll
        for (int d = 0; d < 12; ++d) {
            float a2 = __shfl_xor(A[d], off, 64);
            A[d] = A[d] * c1 + a2 * c2;
        }
        m = nm;
    }

    float inv = den > 0.f ? 1.f / den : 0.f;
    float* op = hout + (size_t)n * 96 + hd * 12;
    // each q-lane writes 3 of the 12 outputs
#pragma unroll
    for (int j = 0; j < 3; ++j) {
        int d = q * 3 + j;
        float v = (d == 0) ? A[0] : (d == 1) ? A[1] : (d == 2) ? A[2] : (d == 3) ? A[3]
                : (d == 4) ? A[4] : (d == 5) ? A[5] : (d == 6) ? A[6] : (d == 7) ? A[7]
                : (d == 8) ? A[8] : (d == 9) ? A[9] : (d == 10) ? A[10] : A[11];
        op[d] = fmaxf(v * inv, 0.f);
    }
}

// ---------------- per-graph max readout: stage 1 ----------------
__global__ __launch_bounds__(384) void readout_partial(const float* __restrict__ h,
                                                       const int* __restrict__ graph_id,
                                                       float* __restrict__ partial, int N) {
    __shared__ int lhg[GG * 96];
    int t = threadIdx.x;
    for (int i = t; i < GG * 96; i += 384) lhg[i] = 0;
    __syncthreads();
    int f = t % 96, nl = t / 96;
    for (int n0 = blockIdx.x * 4; n0 < N; n0 += RB * 4) {
        int n = n0 + nl;
        if (n < N) {
            int g = graph_id[n];
            float v = h[(size_t)n * 96 + f];
            atomicMax(&lhg[g * 96 + f], __float_as_int(v));
        }
    }
    __syncthreads();
    for (int i = t; i < GG * 96; i += 384)
        partial[(size_t)blockIdx.x * (GG * 96) + i] = __int_as_float(lhg[i]);
}

// ---------------- readout stage 2: reduce partials ----------------
__global__ void readout_reduce(const float* __restrict__ partial, float* __restrict__ hg) {
    int i = blockIdx.x * 256 + threadIdx.x;
    if (i < GG * 96) {
        float m = 0.f;
        for (int b = 0; b < RB; ++b) m = fmaxf(m, partial[(size_t)b * (GG * 96) + i]);
        hg[i] = m;
    }
}

// ---------------- classifier MLP: one block per graph ----------------
__global__ __launch_bounds__(96) void mlp_kernel(const float* __restrict__ hg,
                                                 const float* __restrict__ Wc1, const float* __restrict__ bc1,
                                                 const float* __restrict__ Wc2, const float* __restrict__ bc2,
                                                 const float* __restrict__ Wc3, const float* __restrict__ bc3,
                                                 float* __restrict__ out) {
    int g = blockIdx.x;
    int t = threadIdx.x;
    __shared__ float z0[96], z1[96], z2[48];
    z0[t] = hg[(size_t)g * 96 + t];
    __syncthreads();
    float s = bc1[t];
    for (int k = 0; k < 96; ++k) s = fmaf(z0[k], Wc1[k * 96 + t], s);
    z1[t] = fmaxf(s, 0.f);
    __syncthreads();
    if (t < 48) {
        float s2 = bc2[t];
        for (int k = 0; k < 96; ++k) s2 = fmaf(z1[k], Wc2[k * 48 + t], s2);
        z2[t] = fmaxf(s2, 0.f);
    }
    __syncthreads();
    if (t < 10) {
        float s3 = bc3[t];
        for (int k = 0; k < 48; ++k) s3 = fmaf(z2[k], Wc3[k * 10 + t], s3);
        out[(size_t)g * 10 + t] = s3;
    }
}

extern "C" void kernel_launch(void* const* d_in, const int* in_sizes, int n_in,
                              void* d_out, int out_size, void* d_ws, size_t ws_size,
                              hipStream_t stream) {
    const float* x        = (const float*)d_in[0];
    const int*   src      = (const int*)d_in[1];
    const int*   dst      = (const int*)d_in[2];
    const int*   graph_id = (const int*)d_in[3];
    const float* W1  = (const float*)d_in[4];
    const float* b1  = (const float*)d_in[5];
    const float* W2  = (const float*)d_in[6];
    const float* b2  = (const float*)d_in[7];
    const float* Ws  = (const float*)d_in[8];
    const float* bs  = (const float*)d_in[9];
    const float* Wd  = (const float*)d_in[10];
    const float* bd  = (const float*)d_in[11];
    const float* attn = (const float*)d_in[12];
    const float* Wc1 = (const float*)d_in[13];
    const float* bc1 = (const float*)d_in[14];
    const float* Wc2 = (const float*)d_in[15];
    const float* bc2 = (const float*)d_in[16];
    const float* Wc3 = (const float*)d_in[17];
    const float* bc3 = (const float*)d_in[18];
    float* out = (float*)d_out;

    char* ws = (char*)d_ws;
    size_t off = 0;
    auto alloc = [&](size_t bytes) {
        char* p = ws + off;
        off = (off + bytes + 255) & ~(size_t)255;
        return p;
    };
    int*   cnt_in    = (int*)alloc(Nn * 4);
    int*   row_start = (int*)alloc((Nn + 1) * 4);
    unsigned char* edge_slot = (unsigned char*)alloc(Ee);
    int*   csr_src   = (int*)alloc(Ee * 4);
    int*   perm      = (int*)alloc(Nn * 4);
    float* degI_is   = (float*)alloc(Nn * 4);
    float* degO_is   = (float*)alloc(Nn * 4);
    float* bufH      = (float*)alloc((size_t)Nn * 96 * 4);
    float* bufT      = (float*)alloc((size_t)Nn * 96 * 4);
    float* bufFd     = (float*)alloc((size_t)Nn * 96 * 4);
    float* hg        = (float*)alloc(GG * 96 * 4);
    float* partial   = (float*)alloc((size_t)RB * GG * 96 * 4);
    int*   blk_sum   = (int*)alloc(128 * 4);
    int*   blk_off   = (int*)alloc(128 * 4);
    int*   dcnt      = (int*)alloc(DBIN * 4);
    int*   dcur      = (int*)alloc(DBIN * 4);

    // packed histogram partials alias the (not-yet-used) feature buffers:
    // HCHK*NW*4 = 12.8 MB each; bufT/bufFd are 19.2 MB each.
    unsigned int* partS = (unsigned int*)bufT;
    unsigned int* partD = (unsigned int*)bufFd;

    hipMemsetAsync(dcnt, 0, DBIN * 4, stream);

    // ---- CSR build + degrees + degree-sort (no global fp atomics, 6 kernels) ----
    hist_lds<<<HCHK, 512, 0, stream>>>(src, dst, partS, partD, edge_slot);
    hist_scan<<<(NW + 255) / 256, 256, 0, stream>>>(partD, partS, cnt_in, degI_is, degO_is, dcnt);
    scan1_kernel<<<SCAN_BLOCKS, 256, 0, stream>>>(cnt_in, row_start, blk_sum, Nn);
    scan2_kernel<<<2, 128, 0, stream>>>(blk_sum, blk_off, row_start, dcnt, dcur, Nn);
    scan3_kernel<<<SCAN_BLOCKS + NSB, 256, 0, stream>>>(row_start, blk_off, cnt_in, dcur, perm, Nn);
    fill_kernel<<<HCHK, 512, 0, stream>>>(src, dst, row_start, partD, edge_slot, csr_src);

    int gemm_blocks = (Nn + 63) / 64;
    int agg_blocks  = (Nn * 24 + 191) / 192;
    int gat_blocks  = (Nn * 32 + 255) / 256;           // 4-way edge-split: 32 threads/node

    // GraphConv 1: x[N,128] -> bufH
    gemm96<<<gemm_blocks, 192, 0, stream>>>(x, 128, W1, nullptr, degO_is, bufT, Nn);
    gc_agg<<<agg_blocks, 192, 0, stream>>>(bufT, row_start, csr_src, degI_is, b1, perm, bufH, Nn);
    // GraphConv 2
    gemm96<<<gemm_blocks, 192, 0, stream>>>(bufH, 96, W2, nullptr, degO_is, bufT, Nn);
    gc_agg<<<agg_blocks, 192, 0, stream>>>(bufT, row_start, csr_src, degI_is, b2, perm, bufH, Nn);

    // 3x GATv2: fused dual GEMM (fs,fd) then fused attention+aggregate
    for (int l = 0; l < 3; ++l) {
        const float* Wsl = Ws + (size_t)l * 96 * 96;
        const float* bsl = bs + (size_t)l * 96;
        const float* Wdl = Wd + (size_t)l * 96 * 96;
        const float* bdl = bd + (size_t)l * 96;
        const float* atl = attn + (size_t)l * 96;
        gemm96x2<<<gemm_blocks, 192, 0, stream>>>(bufH, Wsl, bsl, Wdl, bdl, bufT, bufFd, Nn);
        gat_agg<<<gat_blocks, 256, 0, stream>>>(bufT, bufFd, atl, row_start, csr_src, perm, bufH, Nn);
    }

    readout_partial<<<RB, 384, 0, stream>>>(bufH, graph_id, partial, Nn);
    readout_reduce<<<(GG * 96 + 255) / 256, 256, 0, stream>>>(partial, hg);
    mlp_kernel<<<GG, 96, 0, stream>>>(hg, Wc1, bc1, Wc2, bc2, Wc3, bc3, out);
}

// Round 8
// 617.261 us; speedup vs baseline: 1.1547x; 1.0076x over previous
//
#include <hip/hip_runtime.h>
#include <hip/hip_bf16.h>

#define Nn 50000
#define Ee 800000
#define INF_ 128
#define HIDF 96
#define HH 8
#define DD 12
#define GG 64
#define OUTF 10

#define SCAN_CHUNK 512
#define SCAN_BLOCKS ((Nn + SCAN_CHUNK - 1) / SCAN_CHUNK)   // 98
#define NSB ((Nn + 255) / 256)                             // 196
#define RB 128   // readout partial blocks

// byte-packed LDS histogram CSR build
#define HCHK 256                // edge chunks (= blocks)
#define HCHKE (Ee / HCHK)       // 3125 edges per chunk
#define NW 12512                // packed words: 4 keys/word, 50048 >= Nn
#define DBIN 64                 // degree bins for counting sort
#define HSB (NW / 32)           // 391 hist_scan blocks (exact: 391*32 = 12512)

// ---------------- hist pass A: single-pass dual byte-packed LDS histograms ----------------
__global__ __launch_bounds__(512) void hist_lds(const int* __restrict__ src,
                                                const int* __restrict__ dst,
                                                unsigned int* __restrict__ partS,
                                                unsigned int* __restrict__ partD,
                                                unsigned char* __restrict__ edge_slot) {
    __shared__ unsigned int hS[NW];
    __shared__ unsigned int hD[NW];
    int b = blockIdx.x, t = threadIdx.x;
    for (int i = t; i < NW; i += 512) { hS[i] = 0u; hD[i] = 0u; }
    __syncthreads();
    int base = b * HCHKE;
    for (int i = t; i < HCHKE; i += 512) {
        int d = dst[base + i];
        unsigned int old = atomicAdd(&hD[d >> 2], 1u << ((d & 3) * 8));
        edge_slot[base + i] = (unsigned char)((old >> ((d & 3) * 8)) & 0xFFu);
        int s = src[base + i];
        atomicAdd(&hS[s >> 2], 1u << ((s & 3) * 8));
    }
    __syncthreads();
    for (int i = t; i < NW; i += 512) {
        partD[(size_t)b * NW + i] = hD[i];
        partS[(size_t)b * NW + i] = hS[i];
    }
}

// ---------------- hist pass B: SEGMENTED chunk-prefix ----------------
// R7 analysis: old version was 49 blocks x 256 threads (0.2 blocks/CU) with a
// 256-iteration serial chain per thread -> latency-bound on ~600cy cross-XCD
// reads. Split each w's scan across 8 segment-threads (32 chunks each, values
// held in statically-indexed registers), exchange segment sums via LDS,
// write back exclusive prefixes from registers. 391 blocks, chain length 32.
// Byte-packed adds are associative -> bit-identical partD/cnt/deg outputs.
__global__ __launch_bounds__(256) void hist_scan(unsigned int* __restrict__ partD,
                                                 const unsigned int* __restrict__ partS,
                                                 int* __restrict__ cnt_in,
                                                 float* __restrict__ degI_is,
                                                 float* __restrict__ degO_is,
                                                 int* __restrict__ dcnt) {
    __shared__ unsigned int sumD[8][32];
    __shared__ unsigned int sumS[8][32];
    __shared__ int hbin[DBIN];
    const int t = threadIdx.x;
    const int wl = t & 31;          // w within block (consecutive lanes -> coalesced)
    const int seg = t >> 5;         // chunk segment 0..7
    const int w = blockIdx.x * 32 + wl;
    if (t < DBIN) hbin[t] = 0;

    unsigned int v[32];
    unsigned int sD = 0u, sS = 0u;
    const size_t base = (size_t)(seg * 32) * NW + w;
#pragma unroll
    for (int c = 0; c < 32; ++c) {
        size_t idx = base + (size_t)c * NW;
        v[c] = partD[idx];
        sD += v[c];
        sS += partS[idx];
    }
    sumD[seg][wl] = sD;
    sumS[seg][wl] = sS;
    __syncthreads();

    unsigned int excl = 0u;
#pragma unroll
    for (int s = 0; s < 8; ++s)
        if (s < seg) excl += sumD[s][wl];
#pragma unroll
    for (int c = 0; c < 32; ++c) {
        size_t idx = base + (size_t)c * NW;
        partD[idx] = excl;          // exclusive prefix across chunks (packed bytes)
        excl += v[c];
    }

    if (seg == 7) {
        unsigned int totD = 0u, totS = 0u;
#pragma unroll
        for (int s = 0; s < 8; ++s) { totD += sumD[s][wl]; totS += sumS[s][wl]; }
#pragma unroll
        for (int j = 0; j < 4; ++j) {
            int k = w * 4 + j;
            if (k < Nn) {
                int di = (int)((totD >> (j * 8)) & 0xFFu);
                int dо = (int)((totS >> (j * 8)) & 0xFFu);
                cnt_in[k] = di;
                degI_is[k] = rsqrtf((float)max(di, 1));
                degO_is[k] = rsqrtf((float)max(dо, 1));
                atomicAdd(&hbin[DBIN - 1 - min(di, DBIN - 1)], 1);
            }
        }
    }
    __syncthreads();
    if (t < DBIN && hbin[t]) atomicAdd(&dcnt[t], hbin[t]);
}

// ---------------- hierarchical scan, stage 1 ----------------
__global__ __launch_bounds__(256) void scan1_kernel(const int* __restrict__ cnt,
                                                    int* __restrict__ row_start,
                                                    int* __restrict__ blk_sum, int N) {
    __shared__ int part[256];
    int t = threadIdx.x;
    int base = blockIdx.x * SCAN_CHUNK;
    int i0 = base + 2 * t, i1 = i0 + 1;
    int a = (i0 < N) ? cnt[i0] : 0;
    int b = (i1 < N) ? cnt[i1] : 0;
    int s = a + b;
    part[t] = s;
    __syncthreads();
    for (int off = 1; off < 256; off <<= 1) {
        int v = (t >= off) ? part[t - off] : 0;
        __syncthreads();
        part[t] += v;
        __syncthreads();
    }
    int excl = part[t] - s;
    if (i0 < N) row_start[i0] = excl;
    if (i1 < N) row_start[i1] = excl + a;
    if (t == 255) blk_sum[blockIdx.x] = part[255];
}

// ---------------- stage 2 (block 0) + degree-bin scan (block 1) ----------------
__global__ __launch_bounds__(128) void scan2_kernel(const int* __restrict__ blk_sum,
                                                    int* __restrict__ blk_off,
                                                    int* __restrict__ row_start,
                                                    const int* __restrict__ dcnt,
                                                    int* __restrict__ dcur, int N) {
    __shared__ int part[128];
    int t = threadIdx.x;
    if (blockIdx.x == 0) {
        int v0 = (t < SCAN_BLOCKS) ? blk_sum[t] : 0;
        part[t] = v0;
        __syncthreads();
        for (int off = 1; off < 128; off <<= 1) {
            int v = (t >= off) ? part[t - off] : 0;
            __syncthreads();
            part[t] += v;
            __syncthreads();
        }
        blk_off[t] = part[t] - v0;
        if (t == 127) row_start[N] = part[127];
    } else {
        int v0 = (t < DBIN) ? dcnt[t] : 0;
        part[t] = v0;
        __syncthreads();
        for (int off = 1; off < DBIN; off <<= 1) {
            int v = (t >= off) ? part[t - off] : 0;
            __syncthreads();
            part[t] += v;
            __syncthreads();
        }
        if (t < DBIN) dcur[t] = part[t] - v0;   // exclusive
    }
}

// ---------------- stage 3 + perm scatter ----------------
__global__ __launch_bounds__(256) void scan3_kernel(int* __restrict__ row_start,
                                                    const int* __restrict__ blk_off,
                                                    const int* __restrict__ cnt_in,
                                                    int* __restrict__ dcur,
                                                    int* __restrict__ perm, int N) {
    int t = threadIdx.x;
    if (blockIdx.x < SCAN_BLOCKS) {
        int base = blockIdx.x * SCAN_CHUNK;
        int off = blk_off[blockIdx.x];
        int i0 = base + 2 * t, i1 = i0 + 1;
        if (i0 < N) row_start[i0] += off;
        if (i1 < N) row_start[i1] += off;
    } else {
        __shared__ int lh[DBIN];
        __shared__ int lbase[DBIN];
        if (t < DBIN) lh[t] = 0;
        __syncthreads();
        int n = (blockIdx.x - SCAN_BLOCKS) * 256 + t;
        int bin = 0, lslot = 0;
        if (n < N) {
            bin = DBIN - 1 - min(cnt_in[n], DBIN - 1);
            lslot = atomicAdd(&lh[bin], 1);
        }
        __syncthreads();
        if (t < DBIN) lbase[t] = lh[t] ? atomicAdd(&dcur[t], lh[t]) : 0;
        __syncthreads();
        if (n < N) perm[lbase[bin] + lslot] = n;
    }
}

// ---------------- CSR fill: atomic-free ----------------
__global__ __launch_bounds__(512) void fill_kernel(const int* __restrict__ src,
                                                   const int* __restrict__ dst,
                                                   const int* __restrict__ row_start,
                                                   const unsigned int* __restrict__ partD,
                                                   const unsigned char* __restrict__ edge_slot,
                                                   int* __restrict__ csr_src) {
    int b = blockIdx.x, t = threadIdx.x;
    int base = b * HCHKE;
    size_t po = (size_t)b * NW;
    for (int i = t; i < HCHKE; i += 512) {
        int e = base + i;
        int d = dst[e];
        int cb = (int)((partD[po + (d >> 2)] >> ((d & 3) * 8)) & 0xFFu);
        csr_src[row_start[d] + cb + (int)edge_slot[e]] = src[e];
    }
}

// ---------------- chunked-W LDS GEMM: 18.4KB LDS -> high occupancy ----------------
#define KC 48
__global__ __launch_bounds__(192) void gemm96(const float* __restrict__ A, int K,
                                              const float* __restrict__ W,
                                              const float* __restrict__ bias,
                                              const float* __restrict__ rowScale,
                                              float* __restrict__ out, int N) {
    __shared__ float W_lds[KC * 96];   // 18432 B
    const int t = threadIdx.x;
    const int row0 = blockIdx.x * 64;
    const int tcol = t % 24;
    const int trow = t / 24;

    const float* Ap[8];
    float sc[8];
#pragma unroll
    for (int i = 0; i < 8; ++i) {
        int gr = row0 + trow + 8 * i;
        gr = gr < N ? gr : N - 1;           // clamp: garbage rows never stored
        Ap[i] = A + (size_t)gr * K;
        sc[i] = rowScale ? rowScale[gr] : 1.f;
    }
    float acc[8][4];
#pragma unroll
    for (int i = 0; i < 8; ++i)
#pragma unroll
        for (int j = 0; j < 4; ++j) acc[i][j] = 0.f;

    for (int kc = 0; kc < K; kc += KC) {
        int klen = (K - kc) < KC ? (K - kc) : KC;
        __syncthreads();                    // protect previous chunk's readers
        for (int i = t; i < klen * 24; i += 192)
            ((float4*)W_lds)[i] = ((const float4*)W)[kc * 24 + i];
        __syncthreads();
        for (int k = 0; k < klen; k += 4) {
            float4 a[8];
#pragma unroll
            for (int i = 0; i < 8; ++i)
                a[i] = *((const float4*)(Ap[i] + kc + k));
#pragma unroll
            for (int kk = 0; kk < 4; ++kk) {
                float4 wv = *((const float4*)(W_lds + (k + kk) * 96 + tcol * 4));
#pragma unroll
                for (int i = 0; i < 8; ++i) {
                    float av = ((kk == 0) ? a[i].x : (kk == 1) ? a[i].y
                               : (kk == 2) ? a[i].z : a[i].w) * sc[i];
                    acc[i][0] = fmaf(av, wv.x, acc[i][0]);
                    acc[i][1] = fmaf(av, wv.y, acc[i][1]);
                    acc[i][2] = fmaf(av, wv.z, acc[i][2]);
                    acc[i][3] = fmaf(av, wv.w, acc[i][3]);
                }
            }
        }
    }
    float4 b4 = bias ? *((const float4*)(bias + tcol * 4)) : make_float4(0.f, 0.f, 0.f, 0.f);
#pragma unroll
    for (int i = 0; i < 8; ++i) {
        int gr = row0 + trow + 8 * i;
        if (gr < N) {
            float4 o = make_float4(acc[i][0] + b4.x, acc[i][1] + b4.y,
                                   acc[i][2] + b4.z, acc[i][3] + b4.w);
            *((float4*)(out + (size_t)gr * 96 + tcol * 4)) = o;
        }
    }
}

// ---------------- chunked-W dual GEMM (K=96): 2 x 24-k chunks = 18.4KB LDS ----------------
#define KC2 24
__global__ __launch_bounds__(192) void gemm96x2(const float* __restrict__ A,
                                                const float* __restrict__ W1_, const float* __restrict__ b1_,
                                                const float* __restrict__ W2_, const float* __restrict__ b2_,
                                                float* __restrict__ out1, float* __restrict__ out2, int N) {
    __shared__ float W_lds[2 * KC2 * 96];   // 18432 B
    const int t = threadIdx.x;
    const int row0 = blockIdx.x * 64;
    const int tcol = t % 24;
    const int trow = t / 24;

    const float* Ap[8];
#pragma unroll
    for (int i = 0; i < 8; ++i) {
        int gr = row0 + trow + 8 * i;
        gr = gr < N ? gr : N - 1;           // clamp: garbage rows never stored
        Ap[i] = A + (size_t)gr * 96;
    }
    float acc1[8][4], acc2[8][4];
#pragma unroll
    for (int i = 0; i < 8; ++i)
#pragma unroll
        for (int j = 0; j < 4; ++j) { acc1[i][j] = 0.f; acc2[i][j] = 0.f; }

    for (int kc = 0; kc < 96; kc += KC2) {
        __syncthreads();                    // protect previous chunk's readers
        for (int i = t; i < KC2 * 24; i += 192) {
            ((float4*)W_lds)[i] = ((const float4*)W1_)[kc * 24 + i];
            ((float4*)(W_lds + KC2 * 96))[i] = ((const float4*)W2_)[kc * 24 + i];
        }
        __syncthreads();
        for (int k = 0; k < KC2; k += 4) {
            float4 a[8];
#pragma unroll
            for (int i = 0; i < 8; ++i)
                a[i] = *((const float4*)(Ap[i] + kc + k));
#pragma unroll
            for (int kk = 0; kk < 4; ++kk) {
                float4 wv1 = *((const float4*)(W_lds + (k + kk) * 96 + tcol * 4));
                float4 wv2 = *((const float4*)(W_lds + KC2 * 96 + (k + kk) * 96 + tcol * 4));
#pragma unroll
                for (int i = 0; i < 8; ++i) {
                    float av = (kk == 0) ? a[i].x : (kk == 1) ? a[i].y : (kk == 2) ? a[i].z : a[i].w;
                    acc1[i][0] = fmaf(av, wv1.x, acc1[i][0]);
                    acc1[i][1] = fmaf(av, wv1.y, acc1[i][1]);
                    acc1[i][2] = fmaf(av, wv1.z, acc1[i][2]);
                    acc1[i][3] = fmaf(av, wv1.w, acc1[i][3]);
                    acc2[i][0] = fmaf(av, wv2.x, acc2[i][0]);
                    acc2[i][1] = fmaf(av, wv2.y, acc2[i][1]);
                    acc2[i][2] = fmaf(av, wv2.z, acc2[i][2]);
                    acc2[i][3] = fmaf(av, wv2.w, acc2[i][3]);
                }
            }
        }
    }
    float4 bb1 = *((const float4*)(b1_ + tcol * 4));
    float4 bb2 = *((const float4*)(b2_ + tcol * 4));
#pragma unroll
    for (int i = 0; i < 8; ++i) {
        int gr = row0 + trow + 8 * i;
        if (gr < N) {
            float4 o1 = make_float4(acc1[i][0] + bb1.x, acc1[i][1] + bb1.y,
                                    acc1[i][2] + bb1.z, acc1[i][3] + bb1.w);
            float4 o2 = make_float4(acc2[i][0] + bb2.x, acc2[i][1] + bb2.y,
                                    acc2[i][2] + bb2.z, acc2[i][3] + bb2.w);
            *((float4*)(out1 + (size_t)gr * 96 + tcol * 4)) = o1;
            *((float4*)(out2 + (size_t)gr * 96 + tcol * 4)) = o2;
        }
    }
}

// ---------------- GraphConv aggregate (degree-sorted via perm) ----------------
__global__ __launch_bounds__(192) void gc_agg(const float* __restrict__ hW,
                                              const int* __restrict__ row_start,
                                              const int* __restrict__ csr_src,
                                              const float* __restrict__ degI_is,
                                              const float* __restrict__ bias,
                                              const int* __restrict__ perm,
                                              float* __restrict__ hout, int N) {
    int tid = blockIdx.x * 192 + threadIdx.x;
    int p = tid / 24;
    int c = (tid % 24) * 4;
    if (p >= N) return;
    int n = perm[p];
    int beg = row_start[n], end = row_start[n + 1];
    float4 s = make_float4(0.f, 0.f, 0.f, 0.f);
    int e = beg;
    for (; e + 4 <= end; e += 4) {
        int i0 = csr_src[e], i1 = csr_src[e + 1], i2 = csr_src[e + 2], i3 = csr_src[e + 3];
        float4 v0 = *(const float4*)(hW + (size_t)i0 * 96 + c);
        float4 v1 = *(const float4*)(hW + (size_t)i1 * 96 + c);
        float4 v2 = *(const float4*)(hW + (size_t)i2 * 96 + c);
        float4 v3 = *(const float4*)(hW + (size_t)i3 * 96 + c);
        s.x += (v0.x + v1.x) + (v2.x + v3.x);
        s.y += (v0.y + v1.y) + (v2.y + v3.y);
        s.z += (v0.z + v1.z) + (v2.z + v3.z);
        s.w += (v0.w + v1.w) + (v2.w + v3.w);
    }
    for (; e < end; ++e) {
        int i0 = csr_src[e];
        float4 v0 = *(const float4*)(hW + (size_t)i0 * 96 + c);
        s.x += v0.x; s.y += v0.y; s.z += v0.z; s.w += v0.w;
    }
    float dn = degI_is[n];
    float4 b = *(const float4*)(bias + c);
    float4 o;
    o.x = fmaxf(fmaf(s.x, dn, b.x), 0.f);
    o.y = fmaxf(fmaf(s.y, dn, b.y), 0.f);
    o.z = fmaxf(fmaf(s.z, dn, b.z), 0.f);
    o.w = fmaxf(fmaf(s.w, dn, b.w), 0.f);
    *(float4*)(hout + (size_t)n * 96 + c) = o;
}

// ---------------- GATv2: 4-way edge-split per (node, head), shfl_xor butterfly merge ----------------
// R5/R7: at the random-gather throughput ceiling (~2.9 TB/s); leave as-is.
__global__ __launch_bounds__(256) void gat_agg(const float* __restrict__ fs,
                                               const float* __restrict__ fd,
                                               const float* __restrict__ attn,
                                               const int* __restrict__ row_start,
                                               const int* __restrict__ csr_src,
                                               const int* __restrict__ perm,
                                               float* __restrict__ hout, int N) {
    int tid = blockIdx.x * 256 + threadIdx.x;
    int p = tid >> 5;           // node (perm index)
    int hd = (tid >> 2) & 7;    // head
    int q = tid & 3;            // edge quarter
    if (p >= N) return;
    int n = perm[p];
    float att[12], fdv[12];
    {
        const float4* ap = (const float4*)(attn + hd * 12);
        float4 a0 = ap[0], a1 = ap[1], a2 = ap[2];
        att[0]=a0.x; att[1]=a0.y; att[2]=a0.z; att[3]=a0.w;
        att[4]=a1.x; att[5]=a1.y; att[6]=a1.z; att[7]=a1.w;
        att[8]=a2.x; att[9]=a2.y; att[10]=a2.z; att[11]=a2.w;
        const float4* dp = (const float4*)(fd + (size_t)n * 96 + hd * 12);
        float4 d0 = dp[0], d1 = dp[1], d2 = dp[2];
        fdv[0]=d0.x; fdv[1]=d0.y; fdv[2]=d0.z; fdv[3]=d0.w;
        fdv[4]=d1.x; fdv[5]=d1.y; fdv[6]=d1.z; fdv[7]=d1.w;
        fdv[8]=d2.x; fdv[9]=d2.y; fdv[10]=d2.z; fdv[11]=d2.w;
    }
    int beg = row_start[n], end = row_start[n + 1];
    float m = -3.0e38f, den = 0.f;
    float A[12];
#pragma unroll
    for (int d = 0; d < 12; ++d) A[d] = 0.f;

    for (int e = beg + q; e < end; e += 4) {
        int i0 = csr_src[e];
        const float4* p0 = (const float4*)(fs + (size_t)i0 * 96 + hd * 12);
        float4 s0 = p0[0], s1 = p0[1], s2 = p0[2];
        float fsv[12];
        fsv[0]=s0.x; fsv[1]=s0.y; fsv[2]=s0.z; fsv[3]=s0.w;
        fsv[4]=s1.x; fsv[5]=s1.y; fsv[6]=s1.z; fsv[7]=s1.w;
        fsv[8]=s2.x; fsv[9]=s2.y; fsv[10]=s2.z; fsv[11]=s2.w;
        float logit = 0.f;
#pragma unroll
        for (int d = 0; d < 12; ++d) {
            float u = fsv[d] + fdv[d];
            u = u > 0.f ? u : 0.2f * u;
            logit = fmaf(u, att[d], logit);
        }
        float nm = fmaxf(m, logit);
        float cc = __expf(m - nm);
        float w  = __expf(logit - nm);
        den = fmaf(den, cc, w);
#pragma unroll
        for (int d = 0; d < 12; ++d) A[d] = fmaf(A[d], cc, w * fsv[d]);
        m = nm;
    }

    // butterfly merge across the 4 q-lanes (all lanes end with the full state)
#pragma unroll
    for (int off = 1; off <= 2; off <<= 1) {
        float m2   = __shfl_xor(m, off, 64);
        float den2 = __shfl_xor(den, off, 64);
        float nm = fmaxf(m, m2);
        float c1 = __expf(m - nm);
        float c2 = __expf(m2 - nm);
        den = den * c1 + den2 * c2;
#pragma unroll
        for (int d = 0; d < 12; ++d) {
            float a2 = __shfl_xor(A[d], off, 64);
            A[d] = A[d] * c1 + a2 * c2;
        }
        m = nm;
    }

    float inv = den > 0.f ? 1.f / den : 0.f;
    float* op = hout + (size_t)n * 96 + hd * 12;
    // each q-lane writes 3 of the 12 outputs
#pragma unroll
    for (int j = 0; j < 3; ++j) {
        int d = q * 3 + j;
        float v = (d == 0) ? A[0] : (d == 1) ? A[1] : (d == 2) ? A[2] : (d == 3) ? A[3]
                : (d == 4) ? A[4] : (d == 5) ? A[5] : (d == 6) ? A[6] : (d == 7) ? A[7]
                : (d == 8) ? A[8] : (d == 9) ? A[9] : (d == 10) ? A[10] : A[11];
        op[d] = fmaxf(v * inv, 0.f);
    }
}

// ---------------- per-graph max readout: stage 1 ----------------
__global__ __launch_bounds__(384) void readout_partial(const float* __restrict__ h,
                                                       const int* __restrict__ graph_id,
                                                       float* __restrict__ partial, int N) {
    __shared__ int lhg[GG * 96];
    int t = threadIdx.x;
    for (int i = t; i < GG * 96; i += 384) lhg[i] = 0;
    __syncthreads();
    int f = t % 96, nl = t / 96;
    for (int n0 = blockIdx.x * 4; n0 < N; n0 += RB * 4) {
        int n = n0 + nl;
        if (n < N) {
            int g = graph_id[n];
            float v = h[(size_t)n * 96 + f];
            atomicMax(&lhg[g * 96 + f], __float_as_int(v));
        }
    }
    __syncthreads();
    for (int i = t; i < GG * 96; i += 384)
        partial[(size_t)blockIdx.x * (GG * 96) + i] = __int_as_float(lhg[i]);
}

// ---------------- readout stage 2: reduce partials ----------------
__global__ void readout_reduce(const float* __restrict__ partial, float* __restrict__ hg) {
    int i = blockIdx.x * 256 + threadIdx.x;
    if (i < GG * 96) {
        float m = 0.f;
        for (int b = 0; b < RB; ++b) m = fmaxf(m, partial[(size_t)b * (GG * 96) + i]);
        hg[i] = m;
    }
}

// ---------------- classifier MLP: one block per graph ----------------
__global__ __launch_bounds__(96) void mlp_kernel(const float* __restrict__ hg,
                                                 const float* __restrict__ Wc1, const float* __restrict__ bc1,
                                                 const float* __restrict__ Wc2, const float* __restrict__ bc2,
                                                 const float* __restrict__ Wc3, const float* __restrict__ bc3,
                                                 float* __restrict__ out) {
    int g = blockIdx.x;
    int t = threadIdx.x;
    __shared__ float z0[96], z1[96], z2[48];
    z0[t] = hg[(size_t)g * 96 + t];
    __syncthreads();
    float s = bc1[t];
    for (int k = 0; k < 96; ++k) s = fmaf(z0[k], Wc1[k * 96 + t], s);
    z1[t] = fmaxf(s, 0.f);
    __syncthreads();
    if (t < 48) {
        float s2 = bc2[t];
        for (int k = 0; k < 96; ++k) s2 = fmaf(z1[k], Wc2[k * 48 + t], s2);
        z2[t] = fmaxf(s2, 0.f);
    }
    __syncthreads();
    if (t < 10) {
        float s3 = bc3[t];
        for (int k = 0; k < 48; ++k) s3 = fmaf(z2[k], Wc3[k * 10 + t], s3);
        out[(size_t)g * 10 + t] = s3;
    }
}

extern "C" void kernel_launch(void* const* d_in, const int* in_sizes, int n_in,
                              void* d_out, int out_size, void* d_ws, size_t ws_size,
                              hipStream_t stream) {
    const float* x        = (const float*)d_in[0];
    const int*   src      = (const int*)d_in[1];
    const int*   dst      = (const int*)d_in[2];
    const int*   graph_id = (const int*)d_in[3];
    const float* W1  = (const float*)d_in[4];
    const float* b1  = (const float*)d_in[5];
    const float* W2  = (const float*)d_in[6];
    const float* b2  = (const float*)d_in[7];
    const float* Ws  = (const float*)d_in[8];
    const float* bs  = (const float*)d_in[9];
    const float* Wd  = (const float*)d_in[10];
    const float* bd  = (const float*)d_in[11];
    const float* attn = (const float*)d_in[12];
    const float* Wc1 = (const float*)d_in[13];
    const float* bc1 = (const float*)d_in[14];
    const float* Wc2 = (const float*)d_in[15];
    const float* bc2 = (const float*)d_in[16];
    const float* Wc3 = (const float*)d_in[17];
    const float* bc3 = (const float*)d_in[18];
    float* out = (float*)d_out;

    char* ws = (char*)d_ws;
    size_t off = 0;
    auto alloc = [&](size_t bytes) {
        char* p = ws + off;
        off = (off + bytes + 255) & ~(size_t)255;
        return p;
    };
    int*   cnt_in    = (int*)alloc(Nn * 4);
    int*   row_start = (int*)alloc((Nn + 1) * 4);
    unsigned char* edge_slot = (unsigned char*)alloc(Ee);
    int*   csr_src   = (int*)alloc(Ee * 4);
    int*   perm      = (int*)alloc(Nn * 4);
    float* degI_is   = (float*)alloc(Nn * 4);
    float* degO_is   = (float*)alloc(Nn * 4);
    float* bufH      = (float*)alloc((size_t)Nn * 96 * 4);
    float* bufT      = (float*)alloc((size_t)Nn * 96 * 4);
    float* bufFd     = (float*)alloc((size_t)Nn * 96 * 4);
    float* hg        = (float*)alloc(GG * 96 * 4);
    float* partial   = (float*)alloc((size_t)RB * GG * 96 * 4);
    int*   blk_sum   = (int*)alloc(128 * 4);
    int*   blk_off   = (int*)alloc(128 * 4);
    int*   dcnt      = (int*)alloc(DBIN * 4);
    int*   dcur      = (int*)alloc(DBIN * 4);

    // packed histogram partials alias the (not-yet-used) feature buffers:
    // HCHK*NW*4 = 12.8 MB each; bufT/bufFd are 19.2 MB each.
    unsigned int* partS = (unsigned int*)bufT;
    unsigned int* partD = (unsigned int*)bufFd;

    hipMemsetAsync(dcnt, 0, DBIN * 4, stream);

    // ---- CSR build + degrees + degree-sort (no global fp atomics, 6 kernels) ----
    hist_lds<<<HCHK, 512, 0, stream>>>(src, dst, partS, partD, edge_slot);
    hist_scan<<<HSB, 256, 0, stream>>>(partD, partS, cnt_in, degI_is, degO_is, dcnt);
    scan1_kernel<<<SCAN_BLOCKS, 256, 0, stream>>>(cnt_in, row_start, blk_sum, Nn);
    scan2_kernel<<<2, 128, 0, stream>>>(blk_sum, blk_off, row_start, dcnt, dcur, Nn);
    scan3_kernel<<<SCAN_BLOCKS + NSB, 256, 0, stream>>>(row_start, blk_off, cnt_in, dcur, perm, Nn);
    fill_kernel<<<HCHK, 512, 0, stream>>>(src, dst, row_start, partD, edge_slot, csr_src);

    int gemm_blocks = (Nn + 63) / 64;
    int agg_blocks  = (Nn * 24 + 191) / 192;
    int gat_blocks  = (Nn * 32 + 255) / 256;           // 4-way edge-split: 32 threads/node

    // GraphConv 1: x[N,128] -> bufH
    gemm96<<<gemm_blocks, 192, 0, stream>>>(x, 128, W1, nullptr, degO_is, bufT, Nn);
    gc_agg<<<agg_blocks, 192, 0, stream>>>(bufT, row_start, csr_src, degI_is, b1, perm, bufH, Nn);
    // GraphConv 2
    gemm96<<<gemm_blocks, 192, 0, stream>>>(bufH, 96, W2, nullptr, degO_is, bufT, Nn);
    gc_agg<<<agg_blocks, 192, 0, stream>>>(bufT, row_start, csr_src, degI_is, b2, perm, bufH, Nn);

    // 3x GATv2: fused dual GEMM (fs,fd) then fused attention+aggregate
    for (int l = 0; l < 3; ++l) {
        const float* Wsl = Ws + (size_t)l * 96 * 96;
        const float* bsl = bs + (size_t)l * 96;
        const float* Wdl = Wd + (size_t)l * 96 * 96;
        const float* bdl = bd + (size_t)l * 96;
        const float* atl = attn + (size_t)l * 96;
        gemm96x2<<<gemm_blocks, 192, 0, stream>>>(bufH, Wsl, bsl, Wdl, bdl, bufT, bufFd, Nn);
        gat_agg<<<gat_blocks, 256, 0, stream>>>(bufT, bufFd, atl, row_start, csr_src, perm, bufH, Nn);
    }

    readout_partial<<<RB, 384, 0, stream>>>(bufH, graph_id, partial, Nn);
    readout_reduce<<<(GG * 96 + 255) / 256, 256, 0, stream>>>(partial, hg);
    mlp_kernel<<<GG, 96, 0, stream>>>(hg, Wc1, bc1, Wc2, bc2, Wc3, bc3, out);
}

// Round 9
// 544.336 us; speedup vs baseline: 1.3094x; 1.1340x over previous
//
#include <hip/hip_runtime.h>
#include <hip/hip_bf16.h>
#include <hip/hip_fp16.h>

#define Nn 50000
#define Ee 800000
#define INF_ 128
#define HIDF 96
#define HH 8
#define DD 12
#define GG 64
#define OUTF 10

#define SCAN_CHUNK 512
#define SCAN_BLOCKS ((Nn + SCAN_CHUNK - 1) / SCAN_CHUNK)   // 98
#define NSB ((Nn + 255) / 256)                             // 196
#define RB 128   // readout partial blocks

// byte-packed LDS histogram CSR build
#define HCHK 256                // edge chunks (= blocks)
#define HCHKE (Ee / HCHK)       // 3125 edges per chunk
#define NW 12512                // packed words: 4 keys/word, 50048 >= Nn
#define DBIN 64                 // degree bins for counting sort
#define HSB (NW / 32)           // 391 hist_scan blocks (exact: 391*32 = 12512)

// fp16 pack/unpack helpers (gathered-operand compression; math stays fp32)
__device__ __forceinline__ unsigned int f2h(float a, float b) {
    __half2 h = __floats2half2_rn(a, b);
    return *reinterpret_cast<unsigned int*>(&h);
}
__device__ __forceinline__ float2 h2f(unsigned int u) {
    __half2 h = *reinterpret_cast<__half2*>(&u);
    return __half22float2(h);
}

// ---------------- hist pass A: single-pass dual byte-packed LDS histograms ----------------
__global__ __launch_bounds__(512) void hist_lds(const int* __restrict__ src,
                                                const int* __restrict__ dst,
                                                unsigned int* __restrict__ partS,
                                                unsigned int* __restrict__ partD,
                                                unsigned char* __restrict__ edge_slot) {
    __shared__ unsigned int hS[NW];
    __shared__ unsigned int hD[NW];
    int b = blockIdx.x, t = threadIdx.x;
    for (int i = t; i < NW; i += 512) { hS[i] = 0u; hD[i] = 0u; }
    __syncthreads();
    int base = b * HCHKE;
    for (int i = t; i < HCHKE; i += 512) {
        int d = dst[base + i];
        unsigned int old = atomicAdd(&hD[d >> 2], 1u << ((d & 3) * 8));
        edge_slot[base + i] = (unsigned char)((old >> ((d & 3) * 8)) & 0xFFu);
        int s = src[base + i];
        atomicAdd(&hS[s >> 2], 1u << ((s & 3) * 8));
    }
    __syncthreads();
    for (int i = t; i < NW; i += 512) {
        partD[(size_t)b * NW + i] = hD[i];
        partS[(size_t)b * NW + i] = hS[i];
    }
}

// ---------------- hist pass B: SEGMENTED chunk-prefix (R8) ----------------
__global__ __launch_bounds__(256) void hist_scan(unsigned int* __restrict__ partD,
                                                 const unsigned int* __restrict__ partS,
                                                 int* __restrict__ cnt_in,
                                                 float* __restrict__ degI_is,
                                                 float* __restrict__ degO_is,
                                                 int* __restrict__ dcnt) {
    __shared__ unsigned int sumD[8][32];
    __shared__ unsigned int sumS[8][32];
    __shared__ int hbin[DBIN];
    const int t = threadIdx.x;
    const int wl = t & 31;
    const int seg = t >> 5;
    const int w = blockIdx.x * 32 + wl;
    if (t < DBIN) hbin[t] = 0;

    unsigned int v[32];
    unsigned int sD = 0u, sS = 0u;
    const size_t base = (size_t)(seg * 32) * NW + w;
#pragma unroll
    for (int c = 0; c < 32; ++c) {
        size_t idx = base + (size_t)c * NW;
        v[c] = partD[idx];
        sD += v[c];
        sS += partS[idx];
    }
    sumD[seg][wl] = sD;
    sumS[seg][wl] = sS;
    __syncthreads();

    unsigned int excl = 0u;
#pragma unroll
    for (int s = 0; s < 8; ++s)
        if (s < seg) excl += sumD[s][wl];
#pragma unroll
    for (int c = 0; c < 32; ++c) {
        size_t idx = base + (size_t)c * NW;
        partD[idx] = excl;
        excl += v[c];
    }

    if (seg == 7) {
        unsigned int totD = 0u, totS = 0u;
#pragma unroll
        for (int s = 0; s < 8; ++s) { totD += sumD[s][wl]; totS += sumS[s][wl]; }
#pragma unroll
        for (int j = 0; j < 4; ++j) {
            int k = w * 4 + j;
            if (k < Nn) {
                int di = (int)((totD >> (j * 8)) & 0xFFu);
                int dо = (int)((totS >> (j * 8)) & 0xFFu);
                cnt_in[k] = di;
                degI_is[k] = rsqrtf((float)max(di, 1));
                degO_is[k] = rsqrtf((float)max(dо, 1));
                atomicAdd(&hbin[DBIN - 1 - min(di, DBIN - 1)], 1);
            }
        }
    }
    __syncthreads();
    if (t < DBIN && hbin[t]) atomicAdd(&dcnt[t], hbin[t]);
}

// ---------------- hierarchical scan, stage 1 ----------------
__global__ __launch_bounds__(256) void scan1_kernel(const int* __restrict__ cnt,
                                                    int* __restrict__ row_start,
                                                    int* __restrict__ blk_sum, int N) {
    __shared__ int part[256];
    int t = threadIdx.x;
    int base = blockIdx.x * SCAN_CHUNK;
    int i0 = base + 2 * t, i1 = i0 + 1;
    int a = (i0 < N) ? cnt[i0] : 0;
    int b = (i1 < N) ? cnt[i1] : 0;
    int s = a + b;
    part[t] = s;
    __syncthreads();
    for (int off = 1; off < 256; off <<= 1) {
        int v = (t >= off) ? part[t - off] : 0;
        __syncthreads();
        part[t] += v;
        __syncthreads();
    }
    int excl = part[t] - s;
    if (i0 < N) row_start[i0] = excl;
    if (i1 < N) row_start[i1] = excl + a;
    if (t == 255) blk_sum[blockIdx.x] = part[255];
}

// ---------------- stage 2 (block 0) + degree-bin scan (block 1) ----------------
__global__ __launch_bounds__(128) void scan2_kernel(const int* __restrict__ blk_sum,
                                                    int* __restrict__ blk_off,
                                                    int* __restrict__ row_start,
                                                    const int* __restrict__ dcnt,
                                                    int* __restrict__ dcur, int N) {
    __shared__ int part[128];
    int t = threadIdx.x;
    if (blockIdx.x == 0) {
        int v0 = (t < SCAN_BLOCKS) ? blk_sum[t] : 0;
        part[t] = v0;
        __syncthreads();
        for (int off = 1; off < 128; off <<= 1) {
            int v = (t >= off) ? part[t - off] : 0;
            __syncthreads();
            part[t] += v;
            __syncthreads();
        }
        blk_off[t] = part[t] - v0;
        if (t == 127) row_start[N] = part[127];
    } else {
        int v0 = (t < DBIN) ? dcnt[t] : 0;
        part[t] = v0;
        __syncthreads();
        for (int off = 1; off < DBIN; off <<= 1) {
            int v = (t >= off) ? part[t - off] : 0;
            __syncthreads();
            part[t] += v;
            __syncthreads();
        }
        if (t < DBIN) dcur[t] = part[t] - v0;   // exclusive
    }
}

// ---------------- stage 3 + perm scatter ----------------
__global__ __launch_bounds__(256) void scan3_kernel(int* __restrict__ row_start,
                                                    const int* __restrict__ blk_off,
                                                    const int* __restrict__ cnt_in,
                                                    int* __restrict__ dcur,
                                                    int* __restrict__ perm, int N) {
    int t = threadIdx.x;
    if (blockIdx.x < SCAN_BLOCKS) {
        int base = blockIdx.x * SCAN_CHUNK;
        int off = blk_off[blockIdx.x];
        int i0 = base + 2 * t, i1 = i0 + 1;
        if (i0 < N) row_start[i0] += off;
        if (i1 < N) row_start[i1] += off;
    } else {
        __shared__ int lh[DBIN];
        __shared__ int lbase[DBIN];
        if (t < DBIN) lh[t] = 0;
        __syncthreads();
        int n = (blockIdx.x - SCAN_BLOCKS) * 256 + t;
        int bin = 0, lslot = 0;
        if (n < N) {
            bin = DBIN - 1 - min(cnt_in[n], DBIN - 1);
            lslot = atomicAdd(&lh[bin], 1);
        }
        __syncthreads();
        if (t < DBIN) lbase[t] = lh[t] ? atomicAdd(&dcur[t], lh[t]) : 0;
        __syncthreads();
        if (n < N) perm[lbase[bin] + lslot] = n;
    }
}

// ---------------- CSR fill: atomic-free ----------------
__global__ __launch_bounds__(512) void fill_kernel(const int* __restrict__ src,
                                                   const int* __restrict__ dst,
                                                   const int* __restrict__ row_start,
                                                   const unsigned int* __restrict__ partD,
                                                   const unsigned char* __restrict__ edge_slot,
                                                   int* __restrict__ csr_src) {
    int b = blockIdx.x, t = threadIdx.x;
    int base = b * HCHKE;
    size_t po = (size_t)b * NW;
    for (int i = t; i < HCHKE; i += 512) {
        int e = base + i;
        int d = dst[e];
        int cb = (int)((partD[po + (d >> 2)] >> ((d & 3) * 8)) & 0xFFu);
        csr_src[row_start[d] + cb + (int)edge_slot[e]] = src[e];
    }
}

// ---------------- chunked-W LDS GEMM, fp16 output (gathered downstream) ----------------
// out16[N x 96] (fp16) = fp16( diag(rowScale) * A[N x K] @ W[K x 96] )
// R9: the downstream gc_agg gathers these rows randomly; fp16 halves the
// random-line HBM footprint (192->96 B/row). All FMA accumulation fp32,
// identical k-order; single rn-round at the write.
#define KC 48
__global__ __launch_bounds__(192) void gemm96(const float* __restrict__ A, int K,
                                              const float* __restrict__ W,
                                              const float* __restrict__ rowScale,
                                              __half* __restrict__ out16, int N) {
    __shared__ float W_lds[KC * 96];   // 18432 B
    const int t = threadIdx.x;
    const int row0 = blockIdx.x * 64;
    const int tcol = t % 24;
    const int trow = t / 24;

    const float* Ap[8];
    float sc[8];
#pragma unroll
    for (int i = 0; i < 8; ++i) {
        int gr = row0 + trow + 8 * i;
        gr = gr < N ? gr : N - 1;           // clamp: garbage rows never stored
        Ap[i] = A + (size_t)gr * K;
        sc[i] = rowScale ? rowScale[gr] : 1.f;
    }
    float acc[8][4];
#pragma unroll
    for (int i = 0; i < 8; ++i)
#pragma unroll
        for (int j = 0; j < 4; ++j) acc[i][j] = 0.f;

    for (int kc = 0; kc < K; kc += KC) {
        int klen = (K - kc) < KC ? (K - kc) : KC;
        __syncthreads();                    // protect previous chunk's readers
        for (int i = t; i < klen * 24; i += 192)
            ((float4*)W_lds)[i] = ((const float4*)W)[kc * 24 + i];
        __syncthreads();
        for (int k = 0; k < klen; k += 4) {
            float4 a[8];
#pragma unroll
            for (int i = 0; i < 8; ++i)
                a[i] = *((const float4*)(Ap[i] + kc + k));
#pragma unroll
            for (int kk = 0; kk < 4; ++kk) {
                float4 wv = *((const float4*)(W_lds + (k + kk) * 96 + tcol * 4));
#pragma unroll
                for (int i = 0; i < 8; ++i) {
                    float av = ((kk == 0) ? a[i].x : (kk == 1) ? a[i].y
                               : (kk == 2) ? a[i].z : a[i].w) * sc[i];
                    acc[i][0] = fmaf(av, wv.x, acc[i][0]);
                    acc[i][1] = fmaf(av, wv.y, acc[i][1]);
                    acc[i][2] = fmaf(av, wv.z, acc[i][2]);
                    acc[i][3] = fmaf(av, wv.w, acc[i][3]);
                }
            }
        }
    }
#pragma unroll
    for (int i = 0; i < 8; ++i) {
        int gr = row0 + trow + 8 * i;
        if (gr < N) {
            uint2 pk;
            pk.x = f2h(acc[i][0], acc[i][1]);
            pk.y = f2h(acc[i][2], acc[i][3]);
            *((uint2*)(out16 + (size_t)gr * 96 + tcol * 4)) = pk;
        }
    }
}

// ---------------- chunked-W dual GEMM (K=96): fs -> fp16, fd -> fp32 ----------------
#define KC2 24
__global__ __launch_bounds__(192) void gemm96x2(const float* __restrict__ A,
                                                const float* __restrict__ W1_, const float* __restrict__ b1_,
                                                const float* __restrict__ W2_, const float* __restrict__ b2_,
                                                __half* __restrict__ out1, float* __restrict__ out2, int N) {
    __shared__ float W_lds[2 * KC2 * 96];   // 18432 B
    const int t = threadIdx.x;
    const int row0 = blockIdx.x * 64;
    const int tcol = t % 24;
    const int trow = t / 24;

    const float* Ap[8];
#pragma unroll
    for (int i = 0; i < 8; ++i) {
        int gr = row0 + trow + 8 * i;
        gr = gr < N ? gr : N - 1;           // clamp: garbage rows never stored
        Ap[i] = A + (size_t)gr * 96;
    }
    float acc1[8][4], acc2[8][4];
#pragma unroll
    for (int i = 0; i < 8; ++i)
#pragma unroll
        for (int j = 0; j < 4; ++j) { acc1[i][j] = 0.f; acc2[i][j] = 0.f; }

    for (int kc = 0; kc < 96; kc += KC2) {
        __syncthreads();                    // protect previous chunk's readers
        for (int i = t; i < KC2 * 24; i += 192) {
            ((float4*)W_lds)[i] = ((const float4*)W1_)[kc * 24 + i];
            ((float4*)(W_lds + KC2 * 96))[i] = ((const float4*)W2_)[kc * 24 + i];
        }
        __syncthreads();
        for (int k = 0; k < KC2; k += 4) {
            float4 a[8];
#pragma unroll
            for (int i = 0; i < 8; ++i)
                a[i] = *((const float4*)(Ap[i] + kc + k));
#pragma unroll
            for (int kk = 0; kk < 4; ++kk) {
                float4 wv1 = *((const float4*)(W_lds + (k + kk) * 96 + tcol * 4));
                float4 wv2 = *((const float4*)(W_lds + KC2 * 96 + (k + kk) * 96 + tcol * 4));
#pragma unroll
                for (int i = 0; i < 8; ++i) {
                    float av = (kk == 0) ? a[i].x : (kk == 1) ? a[i].y : (kk == 2) ? a[i].z : a[i].w;
                    acc1[i][0] = fmaf(av, wv1.x, acc1[i][0]);
                    acc1[i][1] = fmaf(av, wv1.y, acc1[i][1]);
                    acc1[i][2] = fmaf(av, wv1.z, acc1[i][2]);
                    acc1[i][3] = fmaf(av, wv1.w, acc1[i][3]);
                    acc2[i][0] = fmaf(av, wv2.x, acc2[i][0]);
                    acc2[i][1] = fmaf(av, wv2.y, acc2[i][1]);
                    acc2[i][2] = fmaf(av, wv2.z, acc2[i][2]);
                    acc2[i][3] = fmaf(av, wv2.w, acc2[i][3]);
                }
            }
        }
    }
    float4 bb1 = *((const float4*)(b1_ + tcol * 4));
    float4 bb2 = *((const float4*)(b2_ + tcol * 4));
#pragma unroll
    for (int i = 0; i < 8; ++i) {
        int gr = row0 + trow + 8 * i;
        if (gr < N) {
            uint2 pk;
            pk.x = f2h(acc1[i][0] + bb1.x, acc1[i][1] + bb1.y);
            pk.y = f2h(acc1[i][2] + bb1.z, acc1[i][3] + bb1.w);
            *((uint2*)(out1 + (size_t)gr * 96 + tcol * 4)) = pk;
            float4 o2 = make_float4(acc2[i][0] + bb2.x, acc2[i][1] + bb2.y,
                                    acc2[i][2] + bb2.z, acc2[i][3] + bb2.w);
            *((float4*)(out2 + (size_t)gr * 96 + tcol * 4)) = o2;
        }
    }
}

// ---------------- GraphConv aggregate: fp16 gather, fp32 math ----------------
__global__ __launch_bounds__(192) void gc_agg(const __half* __restrict__ hW,
                                              const int* __restrict__ row_start,
                                              const int* __restrict__ csr_src,
                                              const float* __restrict__ degI_is,
                                              const float* __restrict__ bias,
                                              const int* __restrict__ perm,
                                              float* __restrict__ hout, int N) {
    int tid = blockIdx.x * 192 + threadIdx.x;
    int p = tid / 24;
    int c = (tid % 24) * 4;
    if (p >= N) return;
    int n = perm[p];
    int beg = row_start[n], end = row_start[n + 1];
    float4 s = make_float4(0.f, 0.f, 0.f, 0.f);
    auto acc4 = [&](int i0) {
        uint2 u = *((const uint2*)(hW + (size_t)i0 * 96 + c));
        float2 f01 = h2f(u.x), f23 = h2f(u.y);
        s.x += f01.x; s.y += f01.y; s.z += f23.x; s.w += f23.y;
    };
    int e = beg;
    for (; e + 4 <= end; e += 4) {
        int i0 = csr_src[e], i1 = csr_src[e + 1], i2 = csr_src[e + 2], i3 = csr_src[e + 3];
        acc4(i0); acc4(i1); acc4(i2); acc4(i3);
    }
    for (; e < end; ++e) acc4(csr_src[e]);
    float dn = degI_is[n];
    float4 b = *(const float4*)(bias + c);
    float4 o;
    o.x = fmaxf(fmaf(s.x, dn, b.x), 0.f);
    o.y = fmaxf(fmaf(s.y, dn, b.y), 0.f);
    o.z = fmaxf(fmaf(s.z, dn, b.z), 0.f);
    o.w = fmaxf(fmaf(s.w, dn, b.w), 0.f);
    *(float4*)(hout + (size_t)n * 96 + c) = o;
}

// ---------------- GATv2: 4-way edge-split, fp16 fs gather, fp32 softmax ----------------
__global__ __launch_bounds__(256) void gat_agg(const __half* __restrict__ fs,
                                               const float* __restrict__ fd,
                                               const float* __restrict__ attn,
                                               const int* __restrict__ row_start,
                                               const int* __restrict__ csr_src,
                                               const int* __restrict__ perm,
                                               float* __restrict__ hout, int N) {
    int tid = blockIdx.x * 256 + threadIdx.x;
    int p = tid >> 5;           // node (perm index)
    int hd = (tid >> 2) & 7;    // head
    int q = tid & 3;            // edge quarter
    if (p >= N) return;
    int n = perm[p];
    float att[12], fdv[12];
    {
        const float4* ap = (const float4*)(attn + hd * 12);
        float4 a0 = ap[0], a1 = ap[1], a2 = ap[2];
        att[0]=a0.x; att[1]=a0.y; att[2]=a0.z; att[3]=a0.w;
        att[4]=a1.x; att[5]=a1.y; att[6]=a1.z; att[7]=a1.w;
        att[8]=a2.x; att[9]=a2.y; att[10]=a2.z; att[11]=a2.w;
        const float4* dp = (const float4*)(fd + (size_t)n * 96 + hd * 12);
        float4 d0 = dp[0], d1 = dp[1], d2 = dp[2];
        fdv[0]=d0.x; fdv[1]=d0.y; fdv[2]=d0.z; fdv[3]=d0.w;
        fdv[4]=d1.x; fdv[5]=d1.y; fdv[6]=d1.z; fdv[7]=d1.w;
        fdv[8]=d2.x; fdv[9]=d2.y; fdv[10]=d2.z; fdv[11]=d2.w;
    }
    int beg = row_start[n], end = row_start[n + 1];
    float m = -3.0e38f, den = 0.f;
    float A[12];
#pragma unroll
    for (int d = 0; d < 12; ++d) A[d] = 0.f;

    for (int e = beg + q; e < end; e += 4) {
        int i0 = csr_src[e];
        const uint2* pp = (const uint2*)(fs + (size_t)i0 * 96 + hd * 12);
        uint2 u0 = pp[0], u1 = pp[1], u2 = pp[2];
        float fsv[12];
        {
            float2 f;
            f = h2f(u0.x); fsv[0]=f.x; fsv[1]=f.y;
            f = h2f(u0.y); fsv[2]=f.x; fsv[3]=f.y;
            f = h2f(u1.x); fsv[4]=f.x; fsv[5]=f.y;
            f = h2f(u1.y); fsv[6]=f.x; fsv[7]=f.y;
            f = h2f(u2.x); fsv[8]=f.x; fsv[9]=f.y;
            f = h2f(u2.y); fsv[10]=f.x; fsv[11]=f.y;
        }
        float logit = 0.f;
#pragma unroll
        for (int d = 0; d < 12; ++d) {
            float u = fsv[d] + fdv[d];
            u = u > 0.f ? u : 0.2f * u;
            logit = fmaf(u, att[d], logit);
        }
        float nm = fmaxf(m, logit);
        float cc = __expf(m - nm);
        float w  = __expf(logit - nm);
        den = fmaf(den, cc, w);
#pragma unroll
        for (int d = 0; d < 12; ++d) A[d] = fmaf(A[d], cc, w * fsv[d]);
        m = nm;
    }

    // butterfly merge across the 4 q-lanes (all lanes end with the full state)
#pragma unroll
    for (int off = 1; off <= 2; off <<= 1) {
        float m2   = __shfl_xor(m, off, 64);
        float den2 = __shfl_xor(den, off, 64);
        float nm = fmaxf(m, m2);
        float c1 = __expf(m - nm);
        float c2 = __expf(m2 - nm);
        den = den * c1 + den2 * c2;
#pragma unroll
        for (int d = 0; d < 12; ++d) {
            float a2 = __shfl_xor(A[d], off, 64);
            A[d] = A[d] * c1 + a2 * c2;
        }
        m = nm;
    }

    float inv = den > 0.f ? 1.f / den : 0.f;
    float* op = hout + (size_t)n * 96 + hd * 12;
    // each q-lane writes 3 of the 12 outputs
#pragma unroll
    for (int j = 0; j < 3; ++j) {
        int d = q * 3 + j;
        float v = (d == 0) ? A[0] : (d == 1) ? A[1] : (d == 2) ? A[2] : (d == 3) ? A[3]
                : (d == 4) ? A[4] : (d == 5) ? A[5] : (d == 6) ? A[6] : (d == 7) ? A[7]
                : (d == 8) ? A[8] : (d == 9) ? A[9] : (d == 10) ? A[10] : A[11];
        op[d] = fmaxf(v * inv, 0.f);
    }
}

// ---------------- per-graph max readout: stage 1 ----------------
__global__ __launch_bounds__(384) void readout_partial(const float* __restrict__ h,
                                                       const int* __restrict__ graph_id,
                                                       float* __restrict__ partial, int N) {
    __shared__ int lhg[GG * 96];
    int t = threadIdx.x;
    for (int i = t; i < GG * 96; i += 384) lhg[i] = 0;
    __syncthreads();
    int f = t % 96, nl = t / 96;
    for (int n0 = blockIdx.x * 4; n0 < N; n0 += RB * 4) {
        int n = n0 + nl;
        if (n < N) {
            int g = graph_id[n];
            float v = h[(size_t)n * 96 + f];
            atomicMax(&lhg[g * 96 + f], __float_as_int(v));
        }
    }
    __syncthreads();
    for (int i = t; i < GG * 96; i += 384)
        partial[(size_t)blockIdx.x * (GG * 96) + i] = __int_as_float(lhg[i]);
}

// ---------------- readout stage 2: reduce partials ----------------
__global__ void readout_reduce(const float* __restrict__ partial, float* __restrict__ hg) {
    int i = blockIdx.x * 256 + threadIdx.x;
    if (i < GG * 96) {
        float m = 0.f;
        for (int b = 0; b < RB; ++b) m = fmaxf(m, partial[(size_t)b * (GG * 96) + i]);
        hg[i] = m;
    }
}

// ---------------- classifier MLP: one block per graph ----------------
__global__ __launch_bounds__(96) void mlp_kernel(const float* __restrict__ hg,
                                                 const float* __restrict__ Wc1, const float* __restrict__ bc1,
                                                 const float* __restrict__ Wc2, const float* __restrict__ bc2,
                                                 const float* __restrict__ Wc3, const float* __restrict__ bc3,
                                                 float* __restrict__ out) {
    int g = blockIdx.x;
    int t = threadIdx.x;
    __shared__ float z0[96], z1[96], z2[48];
    z0[t] = hg[(size_t)g * 96 + t];
    __syncthreads();
    float s = bc1[t];
    for (int k = 0; k < 96; ++k) s = fmaf(z0[k], Wc1[k * 96 + t], s);
    z1[t] = fmaxf(s, 0.f);
    __syncthreads();
    if (t < 48) {
        float s2 = bc2[t];
        for (int k = 0; k < 96; ++k) s2 = fmaf(z1[k], Wc2[k * 48 + t], s2);
        z2[t] = fmaxf(s2, 0.f);
    }
    __syncthreads();
    if (t < 10) {
        float s3 = bc3[t];
        for (int k = 0; k < 48; ++k) s3 = fmaf(z2[k], Wc3[k * 10 + t], s3);
        out[(size_t)g * 10 + t] = s3;
    }
}

extern "C" void kernel_launch(void* const* d_in, const int* in_sizes, int n_in,
                              void* d_out, int out_size, void* d_ws, size_t ws_size,
                              hipStream_t stream) {
    const float* x        = (const float*)d_in[0];
    const int*   src      = (const int*)d_in[1];
    const int*   dst      = (const int*)d_in[2];
    const int*   graph_id = (const int*)d_in[3];
    const float* W1  = (const float*)d_in[4];
    const float* b1  = (const float*)d_in[5];
    const float* W2  = (const float*)d_in[6];
    const float* b2  = (const float*)d_in[7];
    const float* Ws  = (const float*)d_in[8];
    const float* bs  = (const float*)d_in[9];
    const float* Wd  = (const float*)d_in[10];
    const float* bd  = (const float*)d_in[11];
    const float* attn = (const float*)d_in[12];
    const float* Wc1 = (const float*)d_in[13];
    const float* bc1 = (const float*)d_in[14];
    const float* Wc2 = (const float*)d_in[15];
    const float* bc2 = (const float*)d_in[16];
    const float* Wc3 = (const float*)d_in[17];
    const float* bc3 = (const float*)d_in[18];
    float* out = (float*)d_out;

    char* ws = (char*)d_ws;
    size_t off = 0;
    auto alloc = [&](size_t bytes) {
        char* p = ws + off;
        off = (off + bytes + 255) & ~(size_t)255;
        return p;
    };
    int*   cnt_in    = (int*)alloc(Nn * 4);
    int*   row_start = (int*)alloc((Nn + 1) * 4);
    unsigned char* edge_slot = (unsigned char*)alloc(Ee);
    int*   csr_src   = (int*)alloc(Ee * 4);
    int*   perm      = (int*)alloc(Nn * 4);
    float* degI_is   = (float*)alloc(Nn * 4);
    float* degO_is   = (float*)alloc(Nn * 4);
    float* bufH      = (float*)alloc((size_t)Nn * 96 * 4);
    float* bufT      = (float*)alloc((size_t)Nn * 96 * 4);   // holds fp16 fs/hW (uses half) + aliases partS
    float* bufFd     = (float*)alloc((size_t)Nn * 96 * 4);
    float* hg        = (float*)alloc(GG * 96 * 4);
    float* partial   = (float*)alloc((size_t)RB * GG * 96 * 4);
    int*   blk_sum   = (int*)alloc(128 * 4);
    int*   blk_off   = (int*)alloc(128 * 4);
    int*   dcnt      = (int*)alloc(DBIN * 4);
    int*   dcur      = (int*)alloc(DBIN * 4);

    // packed histogram partials alias the (not-yet-used) feature buffers:
    // HCHK*NW*4 = 12.8 MB each; bufT/bufFd are 19.2 MB each.
    unsigned int* partS = (unsigned int*)bufT;
    unsigned int* partD = (unsigned int*)bufFd;
    __half* bufT16 = (__half*)bufT;

    hipMemsetAsync(dcnt, 0, DBIN * 4, stream);

    // ---- CSR build + degrees + degree-sort (no global fp atomics, 6 kernels) ----
    hist_lds<<<HCHK, 512, 0, stream>>>(src, dst, partS, partD, edge_slot);
    hist_scan<<<HSB, 256, 0, stream>>>(partD, partS, cnt_in, degI_is, degO_is, dcnt);
    scan1_kernel<<<SCAN_BLOCKS, 256, 0, stream>>>(cnt_in, row_start, blk_sum, Nn);
    scan2_kernel<<<2, 128, 0, stream>>>(blk_sum, blk_off, row_start, dcnt, dcur, Nn);
    scan3_kernel<<<SCAN_BLOCKS + NSB, 256, 0, stream>>>(row_start, blk_off, cnt_in, dcur, perm, Nn);
    fill_kernel<<<HCHK, 512, 0, stream>>>(src, dst, row_start, partD, edge_slot, csr_src);

    int gemm_blocks = (Nn + 63) / 64;
    int agg_blocks  = (Nn * 24 + 191) / 192;
    int gat_blocks  = (Nn * 32 + 255) / 256;           // 4-way edge-split: 32 threads/node

    // GraphConv 1: x[N,128] -> bufH
    gemm96<<<gemm_blocks, 192, 0, stream>>>(x, 128, W1, degO_is, bufT16, Nn);
    gc_agg<<<agg_blocks, 192, 0, stream>>>(bufT16, row_start, csr_src, degI_is, b1, perm, bufH, Nn);
    // GraphConv 2
    gemm96<<<gemm_blocks, 192, 0, stream>>>(bufH, 96, W2, degO_is, bufT16, Nn);
    gc_agg<<<agg_blocks, 192, 0, stream>>>(bufT16, row_start, csr_src, degI_is, b2, perm, bufH, Nn);

    // 3x GATv2: fused dual GEMM (fs fp16, fd fp32) then fused attention+aggregate
    for (int l = 0; l < 3; ++l) {
        const float* Wsl = Ws + (size_t)l * 96 * 96;
        const float* bsl = bs + (size_t)l * 96;
        const float* Wdl = Wd + (size_t)l * 96 * 96;
        const float* bdl = bd + (size_t)l * 96;
        const float* atl = attn + (size_t)l * 96;
        gemm96x2<<<gemm_blocks, 192, 0, stream>>>(bufH, Wsl, bsl, Wdl, bdl, bufT16, bufFd, Nn);
        gat_agg<<<gat_blocks, 256, 0, stream>>>(bufT16, bufFd, atl, row_start, csr_src, perm, bufH, Nn);
    }

    readout_partial<<<RB, 384, 0, stream>>>(bufH, graph_id, partial, Nn);
    readout_reduce<<<(GG * 96 + 255) / 256, 256, 0, stream>>>(partial, hg);
    mlp_kernel<<<GG, 96, 0, stream>>>(hg, Wc1, bc1, Wc2, bc2, Wc3, bc3, out);
}